// Round 14
// baseline (752.730 us; speedup 1.0000x reference)
//
#include <hip/hip_runtime.h>
#include <hip/hip_bf16.h>

// Problem constants (from reference)
constexpr int Nn = 20000;   // nodes
constexpr int D  = 256;     // feature dim
constexpr int S  = 4;       // snapshots
constexpr int E  = 320000;  // edges
constexpr int H  = 5;       // horizon
constexpr int L  = 3;       // GCN layers

using bf16 = __hip_bfloat16;
typedef __attribute__((ext_vector_type(8))) short v8s;   // 8 bf16 = 4 VGPRs
typedef __attribute__((ext_vector_type(4))) float v4f;   // MFMA acc

#define GLOBAL_AS __attribute__((address_space(1)))
#define LDS_AS    __attribute__((address_space(3)))

__device__ __forceinline__ float gelu_exact(float x) {
    return 0.5f * x * (1.0f + erff(x * 0.70710678118654752440f));
}
__device__ __forceinline__ unsigned short f2bu(float f) {
    bf16 h = __float2bfloat16(f);
    return *reinterpret_cast<unsigned short*>(&h);
}
__device__ __forceinline__ float b2f(unsigned short u) {
    unsigned int v = (unsigned int)u << 16;
    return __uint_as_float(v);
}
// sign-extend byte k of packed uint -> float
__device__ __forceinline__ float sx0(unsigned int v) { return (float)((int)(v << 24) >> 24); }
__device__ __forceinline__ float sx1(unsigned int v) { return (float)((int)(v << 16) >> 24); }
__device__ __forceinline__ float sx2(unsigned int v) { return (float)((int)(v << 8) >> 24); }
__device__ __forceinline__ float sx3(unsigned int v) { return (float)((int)v >> 24); }

// ---------------- fused preprocessing kernels ----------------
__global__ void init_deg_cnt_kernel(float* deg, int* cnt, int n) {
    int i = blockIdx.x * blockDim.x + threadIdx.x;
    if (i < n) { deg[i] = 1.0f; cnt[i] = 0; }
}
__global__ void deg_hist_kernel(const int* __restrict__ dst, const float* __restrict__ w,
                                float* __restrict__ deg, int* __restrict__ cnt, int e) {
    int i = blockIdx.x * blockDim.x + threadIdx.x;
    if (i < e) {
        int d = dst[i];
        atomicAdd(&deg[d], w[i]);
        atomicAdd(&cnt[d], 1);
    }
}
// 1024-thread exclusive scan over cnt[0..n) -> rowptr[0..n]; zeroes cnt;
// also computes dinv/selfnorm (fused: the distribute loop touches every node).
__global__ __launch_bounds__(1024) void scan_rowptr_kernel(int* __restrict__ cnt,
                                                           int* __restrict__ rowptr,
                                                           const float* __restrict__ deg,
                                                           float* __restrict__ dinv,
                                                           float* __restrict__ selfnorm,
                                                           int n) {
    __shared__ int wsum[16];
    __shared__ int woff[16];
    int t = threadIdx.x;
    int wave = t >> 6, lane = t & 63;
    int chunk = (n + 1023) / 1024;
    int start = t * chunk;
    int end = start + chunk; if (end > n) end = n;
    int s = 0;
    for (int i = start; i < end; ++i) s += cnt[i];
    int incl = s;
#pragma unroll
    for (int off = 1; off < 64; off <<= 1) {
        int v = __shfl_up(incl, off);
        if (lane >= off) incl += v;
    }
    int excl = incl - s;
    if (lane == 63) wsum[wave] = incl;
    __syncthreads();
    if (t == 0) {
        int acc = 0;
        for (int i = 0; i < 16; ++i) { woff[i] = acc; acc += wsum[i]; }
        rowptr[n] = acc;
    }
    __syncthreads();
    int acc = woff[wave] + excl;
    for (int i = start; i < end; ++i) {
        rowptr[i] = acc; acc += cnt[i]; cnt[i] = 0;
        float dg = deg[i];
        float dv = dg > 0.0f ? rsqrtf(fmaxf(dg, 1e-5f)) : 0.0f;
        dinv[i] = dv;
        selfnorm[i] = dv * dv;
    }
}
// fill CSR: csrc (src index) + cnorm (edge norm)
__global__ void csr_fill_kernel(const int* __restrict__ src, const int* __restrict__ dst,
                                const float* __restrict__ w, const float* __restrict__ dinv,
                                const int* __restrict__ rowptr,
                                int* __restrict__ cursor, int* __restrict__ csrc,
                                float* __restrict__ cnorm, int e) {
    int i = blockIdx.x * blockDim.x + threadIdx.x;
    if (i < e) {
        int sN = src[i], dN = dst[i];
        int pos = rowptr[dN] + atomicAdd(&cursor[dN], 1);
        csrc[pos] = sN;
        cnorm[pos] = dinv[sN] * w[i] * dinv[dN];
    }
}
// All weight conversions + GRU bias combine + head weight/bias concat.
constexpr int CW0 = L * D * D;          // gcn_W -> Wtb (transposed)
constexpr int CW1 = CW0 + 3 * D * D;    // Wih
constexpr int CW2 = CW1 + 3 * D * D;    // Whh
constexpr int CW3 = CW2 + 192 * 256;    // fc1W (rows 0-127) + dh1W (rows 128-191)
constexpr int CW4 = CW3 + 64 * 128;     // fc2W
constexpr int CW5 = CW4 + 4 * D;        // gbias: br, bz, big, bhg
constexpr int CW6 = CW5 + 192;          // hcat: fc1b | dh1b
__global__ void convert_weights_kernel(
    const float* __restrict__ gcn_W, const float* __restrict__ Wih,
    const float* __restrict__ Whh, const float* __restrict__ fc1W,
    const float* __restrict__ fc2W, const float* __restrict__ dh1W,
    const float* __restrict__ bih, const float* __restrict__ bhh,
    const float* __restrict__ fc1b, const float* __restrict__ dh1b,
    unsigned short* __restrict__ Wtb, unsigned short* __restrict__ Wihb,
    unsigned short* __restrict__ Whhb, unsigned short* __restrict__ fc1dh1Wb,
    unsigned short* __restrict__ fc2Wb,
    float* __restrict__ gbias, float* __restrict__ hcat)
{
    int i = blockIdx.x * blockDim.x + threadIdx.x;
    if (i < CW0) {
        int l = i / (D * D);
        int rem = i - l * D * D;
        int k = rem / D;
        int n = rem - k * D;
        Wtb[(size_t)l * D * D + (size_t)n * D + k] = f2bu(gcn_W[i]);
    } else if (i < CW1) { int j = i - CW0; Wihb[j] = f2bu(Wih[j]); }
    else if (i < CW2)   { int j = i - CW1; Whhb[j] = f2bu(Whh[j]); }
    else if (i < CW3) {
        int j = i - CW2;
        fc1dh1Wb[j] = (j < 128 * 256) ? f2bu(fc1W[j]) : f2bu(dh1W[j - 128 * 256]);
    }
    else if (i < CW4)   { int j = i - CW3; fc2Wb[j] = f2bu(fc2W[j]); }
    else if (i < CW5) {
        int j = i - CW4;           // 0..1023
        int g = j >> 8, d = j & 255;
        float v;
        if (g == 0)      v = bih[d] + bhh[d];            // br
        else if (g == 1) v = bih[D + d] + bhh[D + d];    // bz
        else if (g == 2) v = bih[2 * D + d];             // big
        else             v = bhh[2 * D + d];             // bhg
        gbias[j] = v;
    }
    else if (i < CW6) {
        int j = i - CW5;           // 0..191
        hcat[j] = (j < 128) ? fc1b[j] : dh1b[j - 128];
    }
}

// ---------------- bf16 MFMA GEMM: C = A[M,K](lda) * B[N,K]^T (+bias) -------------
// OUT_MODE 1: bf16 C[M,N] row-major (store-guarded; gelu if ACT).
// OUT_MODE 3: int8 gather table [node][dim][snap] + per-(node,64-dim-quarter)
//             absmax scale (Cscale[node*4+quarter]); rows gm=node*4+snap.
// XIN 1: A is f32 x [S][Nn][D]; row gm=(node*4+snap) -> x row snap*Nn+node.
// HFUSE 1: waves whose 64-col range == [headColBase, +64) also compute the
//          5-output head: headOut[gm*5+h] = sum_k gelu(C)[gm][headColBase+k]*headW[h][k] + headb[h]
//          via in-quad shfl reduction (removes separate head5 dispatches).
#define GBM 128
#define GBN 128
#define GBK 64
template<int OUT_MODE, int ACT, int XIN, int HFUSE>
__global__ __launch_bounds__(256) void gemm_bt_bf16_kernel(
    const unsigned short* __restrict__ A, int lda,
    const unsigned short* __restrict__ B,
    const float* __restrict__ bias, unsigned short* __restrict__ C,
    float* __restrict__ Cscale,
    const float* __restrict__ headW, const float* __restrict__ headb,
    float* __restrict__ headOut, int headColBase,
    int M, int N, int K)
{
    __shared__ short As[GBM * GBK];
    __shared__ short Bs[GBN * GBK];
    int tid = threadIdx.x;
    int wave = tid >> 6, lane = tid & 63;
    int ln = lane & 15, quad = lane >> 4;
    int wr = wave >> 1, wc = wave & 1;
    int bm = blockIdx.y * GBM, bn = blockIdx.x * GBN;

    v4f acc[4][4];
#pragma unroll
    for (int i = 0; i < 4; ++i)
#pragma unroll
        for (int j = 0; j < 4; ++j)
            acc[i][j] = (v4f)(0.0f);

    int lrow = lane >> 3;          // 0..7 within 8-row segment
    int lcol = (lane & 7) * 8;     // bf16 col offset, 16B chunks

    for (int k0 = 0; k0 < K; k0 += GBK) {
#pragma unroll
        for (int c = 0; c < 4; ++c) {
            int seg = wave * 4 + c;           // 0..15
            int row = seg * 8 + lrow;         // 0..127
            int gm = bm + row; if (gm >= M) gm = M - 1;   // clamp: dup rows, never stored
            if (XIN) {
                int xr = (gm & 3) * Nn + (gm >> 2);
                const float* xp = (const float*)A + (size_t)xr * D + k0 + lcol;
                float4 v0 = *(const float4*)xp;
                float4 v1 = *(const float4*)(xp + 4);
                v8s o;
                o[0] = (short)f2bu(v0.x); o[1] = (short)f2bu(v0.y);
                o[2] = (short)f2bu(v0.z); o[3] = (short)f2bu(v0.w);
                o[4] = (short)f2bu(v1.x); o[5] = (short)f2bu(v1.y);
                o[6] = (short)f2bu(v1.z); o[7] = (short)f2bu(v1.w);
                *(v8s*)(&As[row * GBK + lcol]) = o;
            } else {
                __builtin_amdgcn_global_load_lds(
                    (const GLOBAL_AS unsigned int*)(A + (size_t)gm * lda + k0 + lcol),
                    (LDS_AS unsigned int*)(&As[row * GBK + lcol]), 16, 0, 0);
            }
            int gn = bn + row; if (gn >= N) gn = N - 1;   // clamp for N<128 col-blocks
            __builtin_amdgcn_global_load_lds(
                (const GLOBAL_AS unsigned int*)(B + (size_t)gn * K + k0 + lcol),
                (LDS_AS unsigned int*)(&Bs[row * GBK + lcol]), 16, 0, 0);
        }
        __syncthreads();
#pragma unroll
        for (int ks = 0; ks < 2; ++ks) {
            v8s af[4], bfr[4];
#pragma unroll
            for (int i = 0; i < 4; ++i) {
                int row = wr * 64 + i * 16 + ln;
                af[i] = *(const v8s*)(&As[row * GBK + ks * 32 + quad * 8]);
            }
#pragma unroll
            for (int j = 0; j < 4; ++j) {
                int row = wc * 64 + j * 16 + ln;
                bfr[j] = *(const v8s*)(&Bs[row * GBK + ks * 32 + quad * 8]);
            }
#pragma unroll
            for (int i = 0; i < 4; ++i)
#pragma unroll
                for (int j = 0; j < 4; ++j)
                    acc[i][j] = __builtin_amdgcn_mfma_f32_16x16x32_bf16(af[i], bfr[j], acc[i][j], 0, 0, 0);
        }
        __syncthreads();
    }
    // epilogue: C/D layout col=lane&15, row=quad*4+reg
    if (OUT_MODE == 3) {
#pragma unroll
        for (int i = 0; i < 4; ++i) {
            int gmb = bm + wr * 64 + i * 16 + quad * 4;
            int node = gmb >> 2;
            float mx = 0.0f;
#pragma unroll
            for (int j = 0; j < 4; ++j)
#pragma unroll
                for (int r = 0; r < 4; ++r)
                    mx = fmaxf(mx, fabsf(acc[i][j][r]));
            mx = fmaxf(mx, __shfl_xor(mx, 1));
            mx = fmaxf(mx, __shfl_xor(mx, 2));
            mx = fmaxf(mx, __shfl_xor(mx, 4));
            mx = fmaxf(mx, __shfl_xor(mx, 8));
            float inv = mx > 0.0f ? 127.0f / mx : 0.0f;
#pragma unroll
            for (int j = 0; j < 4; ++j) {
                int gn = bn + wc * 64 + j * 16 + ln;
                int q0 = (int)lrintf(fminf(fmaxf(acc[i][j][0] * inv, -127.0f), 127.0f));
                int q1 = (int)lrintf(fminf(fmaxf(acc[i][j][1] * inv, -127.0f), 127.0f));
                int q2 = (int)lrintf(fminf(fmaxf(acc[i][j][2] * inv, -127.0f), 127.0f));
                int q3 = (int)lrintf(fminf(fmaxf(acc[i][j][3] * inv, -127.0f), 127.0f));
                unsigned int pk = (q0 & 0xff) | ((q1 & 0xff) << 8)
                                | ((q2 & 0xff) << 16) | ((q3 & 0xff) << 24);
                ((unsigned int*)C)[(size_t)node * D + gn] = pk;
            }
            if (ln == 0) {
                int quarter = (bn >> 6) + wc;
                Cscale[(size_t)node * 4 + quarter] = mx * (1.0f / 127.0f);
            }
        }
    } else {
#pragma unroll
        for (int i = 0; i < 4; ++i) {
            int gmb = bm + wr * 64 + i * 16 + quad * 4;
#pragma unroll
            for (int j = 0; j < 4; ++j) {
                int gn = bn + wc * 64 + j * 16 + ln;
                float bv = (bias && gn < N) ? bias[gn] : 0.0f;
                if (gn < N) {
#pragma unroll
                    for (int r = 0; r < 4; ++r) {
                        int gm = gmb + r;
                        if (gm < M) {
                            float v = acc[i][j][r] + bv;
                            if (ACT == 1) v = gelu_exact(v);
                            C[(size_t)gm * N + gn] = f2bu(v);
                        }
                    }
                }
            }
        }
        if (HFUSE && (bn + wc * 64 == headColBase)) {
            // this wave's 64x64 tile feeds the 5-output head
#pragma unroll
            for (int i = 0; i < 4; ++i) {
                float ph[4][5];
#pragma unroll
                for (int r = 0; r < 4; ++r)
#pragma unroll
                    for (int h = 0; h < 5; ++h) ph[r][h] = 0.0f;
#pragma unroll
                for (int j = 0; j < 4; ++j) {
                    int kcol = j * 16 + ln;
                    int gn = headColBase + kcol;
                    float bv = bias ? bias[gn] : 0.0f;
                    float w0 = headW[0 * 64 + kcol];
                    float w1 = headW[1 * 64 + kcol];
                    float w2 = headW[2 * 64 + kcol];
                    float w3 = headW[3 * 64 + kcol];
                    float w4 = headW[4 * 64 + kcol];
#pragma unroll
                    for (int r = 0; r < 4; ++r) {
                        float v = acc[i][j][r] + bv;
                        if (ACT == 1) v = gelu_exact(v);
                        ph[r][0] = fmaf(v, w0, ph[r][0]);
                        ph[r][1] = fmaf(v, w1, ph[r][1]);
                        ph[r][2] = fmaf(v, w2, ph[r][2]);
                        ph[r][3] = fmaf(v, w3, ph[r][3]);
                        ph[r][4] = fmaf(v, w4, ph[r][4]);
                    }
                }
#pragma unroll
                for (int off = 1; off < 16; off <<= 1)
#pragma unroll
                    for (int r = 0; r < 4; ++r)
#pragma unroll
                        for (int h = 0; h < 5; ++h)
                            ph[r][h] += __shfl_xor(ph[r][h], off);
                if (ln == 0) {
                    int gmb = bm + wr * 64 + i * 16 + quad * 4;
#pragma unroll
                    for (int r = 0; r < 4; ++r) {
                        int gm = gmb + r;
                        if (gm < M) {
#pragma unroll
                            for (int h = 0; h < 5; ++h)
                                headOut[(size_t)gm * H + h] = ph[r][h] + headb[h];
                        }
                    }
                }
            }
        }
    }
}

// ---------------- fused GRU step: both GEMMs + gates in one kernel ----------------
// R10-proven 64x64 tile (32 KB LDS, 1252 blocks, no bank conflicts) + `first`
// flag: h==0 on step 0 -> skip the h-phase GEMM entirely, hold = 0.
__global__ __launch_bounds__(256) void gru_fused_kernel(
    const unsigned short* __restrict__ feat, int fstride,   // phase-0 A
    const unsigned short* __restrict__ hbf,                 // phase-1 A  [node][D]
    const unsigned short* __restrict__ Wihb,                // [3*D][D]
    const unsigned short* __restrict__ Whhb,
    const float* __restrict__ gbias,                        // [4*D] br,bz,big,bhg
    float* __restrict__ h, unsigned short* __restrict__ hb,
    int write_f32, int first)
{
    __shared__ short As[64 * 64];     // 8 KB
    __shared__ short Bs[192 * 64];    // 24 KB (3 gates x 64 dims)
    int tid = threadIdx.x;
    int wave = tid >> 6, lane = tid & 63;
    int ln = lane & 15, quad = lane >> 4;
    int wm = wave >> 1, wn = wave & 1;
    int bm = blockIdx.y * 64;
    int bn = blockIdx.x * 64;        // dim block

    v4f accR[2][2], accZ[2][2], accG[2][2], accHG[2][2];
#pragma unroll
    for (int mi = 0; mi < 2; ++mi)
#pragma unroll
        for (int nj = 0; nj < 2; ++nj) {
            accR[mi][nj] = (v4f)(0.0f); accZ[mi][nj] = (v4f)(0.0f);
            accG[mi][nj] = (v4f)(0.0f); accHG[mi][nj] = (v4f)(0.0f);
        }

    int lrow = lane >> 3, lcol = (lane & 7) * 8;
    int nphase = first ? 1 : 2;

    for (int phase = 0; phase < nphase; ++phase) {
        const unsigned short* A = phase ? hbf : feat;
        int astr = phase ? D : fstride;
        const unsigned short* W = phase ? Whhb : Wihb;
        for (int k0 = 0; k0 < D; k0 += 64) {
#pragma unroll
            for (int c = 0; c < 2; ++c) {
                int row = wave * 16 + c * 8 + lrow;
                int gm = bm + row; if (gm >= Nn) gm = Nn - 1;
                __builtin_amdgcn_global_load_lds(
                    (const GLOBAL_AS unsigned int*)(A + (size_t)gm * astr + k0 + lcol),
                    (LDS_AS unsigned int*)(&As[row * 64 + lcol]), 16, 0, 0);
            }
#pragma unroll
            for (int c = 0; c < 6; ++c) {
                int row = wave * 48 + c * 8 + lrow;   // 0..191
                int g = row >> 6, dloc = row & 63;
                __builtin_amdgcn_global_load_lds(
                    (const GLOBAL_AS unsigned int*)(W + ((size_t)(g * D + bn + dloc)) * D + k0 + lcol),
                    (LDS_AS unsigned int*)(&Bs[row * 64 + lcol]), 16, 0, 0);
            }
            __syncthreads();
#pragma unroll
            for (int ks = 0; ks < 2; ++ks) {
                v8s am[2];
#pragma unroll
                for (int mi = 0; mi < 2; ++mi)
                    am[mi] = *(const v8s*)(&As[(wm * 32 + mi * 16 + ln) * 64 + ks * 32 + quad * 8]);
#pragma unroll
                for (int g = 0; g < 3; ++g) {
#pragma unroll
                    for (int nj = 0; nj < 2; ++nj) {
                        v8s bf = *(const v8s*)(&Bs[(g * 64 + wn * 32 + nj * 16 + ln) * 64 + ks * 32 + quad * 8]);
#pragma unroll
                        for (int mi = 0; mi < 2; ++mi) {
                            if (g == 0)
                                accR[mi][nj] = __builtin_amdgcn_mfma_f32_16x16x32_bf16(am[mi], bf, accR[mi][nj], 0, 0, 0);
                            else if (g == 1)
                                accZ[mi][nj] = __builtin_amdgcn_mfma_f32_16x16x32_bf16(am[mi], bf, accZ[mi][nj], 0, 0, 0);
                            else if (phase == 0)
                                accG[mi][nj] = __builtin_amdgcn_mfma_f32_16x16x32_bf16(am[mi], bf, accG[mi][nj], 0, 0, 0);
                            else
                                accHG[mi][nj] = __builtin_amdgcn_mfma_f32_16x16x32_bf16(am[mi], bf, accHG[mi][nj], 0, 0, 0);
                        }
                    }
                }
            }
            __syncthreads();
        }
    }
#pragma unroll
    for (int mi = 0; mi < 2; ++mi) {
        int gm0 = bm + wm * 32 + mi * 16 + quad * 4;
#pragma unroll
        for (int nj = 0; nj < 2; ++nj) {
            int gn = bn + wn * 32 + nj * 16 + ln;
            float vbr = gbias[gn], vbz = gbias[D + gn];
            float vbig = gbias[2 * D + gn], vbhg = gbias[3 * D + gn];
#pragma unroll
            for (int r = 0; r < 4; ++r) {
                int gm = gm0 + r;
                if (gm < Nn) {
                    float rv = 1.0f / (1.0f + expf(-(accR[mi][nj][r] + vbr)));
                    float zv = 1.0f / (1.0f + expf(-(accZ[mi][nj][r] + vbz)));
                    float nv = tanhf(accG[mi][nj][r] + vbig + rv * (accHG[mi][nj][r] + vbhg));
                    float hold = first ? 0.0f : h[(size_t)gm * D + gn];
                    float hv = (1.0f - zv) * nv + zv * hold;
                    if (write_f32) h[(size_t)gm * D + gn] = hv;
                    hb[(size_t)gm * D + gn] = f2bu(hv);
                }
            }
        }
    }
}

// ------- GCN aggregate (4 snapshots, int8 table) + bias + LN + ReLU, wave/node ----
__global__ __launch_bounds__(256) void gcn_agg_ln_relu4_kernel(
    const unsigned int* __restrict__ tbl8, const float4* __restrict__ scales,
    const int* __restrict__ rowptr,
    const int* __restrict__ csrc, const float* __restrict__ cnorm,
    const float* __restrict__ selfnorm,
    const float* __restrict__ gcn_b, const float* __restrict__ ln_g,
    const float* __restrict__ ln_b, unsigned short* __restrict__ out)
{
    int wave = threadIdx.x >> 6, lane = threadIdx.x & 63;
    int i = blockIdx.x * 4 + wave;

    float acc[4][4];   // [q dim-seg][s snap]
    {
        float w = selfnorm[i];
        float4 sc = scales[i];
        float wq[4] = {w * sc.x, w * sc.y, w * sc.z, w * sc.w};
#pragma unroll
        for (int q = 0; q < 4; ++q) {
            unsigned int v = tbl8[(size_t)i * D + lane + q * 64];
            acc[q][0] = wq[q] * sx0(v); acc[q][1] = wq[q] * sx1(v);
            acc[q][2] = wq[q] * sx2(v); acc[q][3] = wq[q] * sx3(v);
        }
    }
    int beg = rowptr[i], end = rowptr[i + 1];
    int p = beg;
    for (; p + 1 < end; p += 2) {
        int sA = csrc[p], sB = csrc[p + 1];
        float wA = cnorm[p], wB = cnorm[p + 1];
        float4 scA = scales[sA], scB = scales[sB];
        unsigned int uA[4], uB[4];
#pragma unroll
        for (int q = 0; q < 4; ++q) {
            uA[q] = tbl8[(size_t)sA * D + lane + q * 64];
            uB[q] = tbl8[(size_t)sB * D + lane + q * 64];
        }
        float wqA[4] = {wA * scA.x, wA * scA.y, wA * scA.z, wA * scA.w};
        float wqB[4] = {wB * scB.x, wB * scB.y, wB * scB.z, wB * scB.w};
#pragma unroll
        for (int q = 0; q < 4; ++q) {
            acc[q][0] = fmaf(wqA[q], sx0(uA[q]), acc[q][0]);
            acc[q][1] = fmaf(wqA[q], sx1(uA[q]), acc[q][1]);
            acc[q][2] = fmaf(wqA[q], sx2(uA[q]), acc[q][2]);
            acc[q][3] = fmaf(wqA[q], sx3(uA[q]), acc[q][3]);
            acc[q][0] = fmaf(wqB[q], sx0(uB[q]), acc[q][0]);
            acc[q][1] = fmaf(wqB[q], sx1(uB[q]), acc[q][1]);
            acc[q][2] = fmaf(wqB[q], sx2(uB[q]), acc[q][2]);
            acc[q][3] = fmaf(wqB[q], sx3(uB[q]), acc[q][3]);
        }
    }
    if (p < end) {
        int sA = csrc[p]; float wA = cnorm[p];
        float4 scA = scales[sA];
        float wqA[4] = {wA * scA.x, wA * scA.y, wA * scA.z, wA * scA.w};
#pragma unroll
        for (int q = 0; q < 4; ++q) {
            unsigned int v = tbl8[(size_t)sA * D + lane + q * 64];
            acc[q][0] = fmaf(wqA[q], sx0(v), acc[q][0]);
            acc[q][1] = fmaf(wqA[q], sx1(v), acc[q][1]);
            acc[q][2] = fmaf(wqA[q], sx2(v), acc[q][2]);
            acc[q][3] = fmaf(wqA[q], sx3(v), acc[q][3]);
        }
    }
#pragma unroll
    for (int q = 0; q < 4; ++q) {
        float bb = gcn_b[lane + q * 64];
        acc[q][0] += bb; acc[q][1] += bb; acc[q][2] += bb; acc[q][3] += bb;
    }
    float s1[4], s2[4];
#pragma unroll
    for (int s = 0; s < 4; ++s) {
        s1[s] = acc[0][s] + acc[1][s] + acc[2][s] + acc[3][s];
        s2[s] = acc[0][s] * acc[0][s] + acc[1][s] * acc[1][s]
              + acc[2][s] * acc[2][s] + acc[3][s] * acc[3][s];
    }
#pragma unroll
    for (int off = 32; off > 0; off >>= 1) {
#pragma unroll
        for (int s = 0; s < 4; ++s) {
            s1[s] += __shfl_xor(s1[s], off);
            s2[s] += __shfl_xor(s2[s], off);
        }
    }
    const float inv = 1.0f / D;
    float m[4], rr[4];
#pragma unroll
    for (int s = 0; s < 4; ++s) {
        m[s] = s1[s] * inv;
        rr[s] = rsqrtf(s2[s] * inv - m[s] * m[s] + 1e-5f);
    }
    size_t ob = (size_t)(i << 2) * D;
#pragma unroll
    for (int q = 0; q < 4; ++q) {
        int d = lane + q * 64;
        float g = ln_g[d], lb = ln_b[d];
#pragma unroll
        for (int s = 0; s < 4; ++s) {
            float y = (acc[q][s] - m[s]) * rr[s] * g + lb;
            out[ob + (size_t)s * D + d] = f2bu(fmaxf(y, 0.0f));
        }
    }
}

extern "C" void kernel_launch(void* const* d_in, const int* in_sizes, int n_in,
                              void* d_out, int out_size, void* d_ws, size_t ws_size,
                              hipStream_t stream)
{
    const float* x     = (const float*)d_in[0];
    const int*   esrc  = (const int*)d_in[1];
    const int*   edst  = (const int*)d_in[2];
    const float* ew    = (const float*)d_in[3];
    const float* gcn_W = (const float*)d_in[4];
    const float* gcn_b = (const float*)d_in[5];
    const float* ln_g  = (const float*)d_in[6];
    const float* ln_b  = (const float*)d_in[7];
    const float* Wih   = (const float*)d_in[8];
    const float* Whh   = (const float*)d_in[9];
    const float* bih   = (const float*)d_in[10];
    const float* bhh   = (const float*)d_in[11];
    const float* fc1W  = (const float*)d_in[12];
    const float* fc1b  = (const float*)d_in[13];
    const float* fc2W  = (const float*)d_in[14];
    const float* fc2b  = (const float*)d_in[15];
    const float* fc3W  = (const float*)d_in[16];
    const float* fc3b  = (const float*)d_in[17];
    const float* dh1W  = (const float*)d_in[18];
    const float* dh1b  = (const float*)d_in[19];
    const float* dh2W  = (const float*)d_in[20];
    const float* dh2b  = (const float*)d_in[21];

    float* out = (float*)d_out;   // [Nn*H forecast][Nn*H direction]

    // workspace carve-out (aligned to 256B); total ~111 MB
    char* p = (char*)d_ws;
    auto alloc = [&](size_t bytes) -> void* {
        void* r = (void*)p;
        p += (bytes + 255) & ~(size_t)255;
        return r;
    };
    float* deg      = (float*)alloc((size_t)Nn * 4);
    float* dinv     = (float*)alloc((size_t)Nn * 4);
    float* selfnorm = (float*)alloc((size_t)Nn * 4);
    int*   rowptr   = (int*)alloc((size_t)(Nn + 1) * 4);
    int*   cnt      = (int*)alloc((size_t)Nn * 4);
    int*   csrc     = (int*)alloc((size_t)E * 4);
    float* cnorm    = (float*)alloc((size_t)E * 4);
    unsigned short* Wtb      = (unsigned short*)alloc((size_t)L * D * D * 2);
    unsigned short* Wihb     = (unsigned short*)alloc((size_t)3 * D * D * 2);
    unsigned short* Whhb     = (unsigned short*)alloc((size_t)3 * D * D * 2);
    unsigned short* fc1dh1Wb = (unsigned short*)alloc((size_t)192 * 256 * 2);
    unsigned short* fc2Wb    = (unsigned short*)alloc((size_t)64 * 128 * 2);
    float* gbias    = (float*)alloc((size_t)4 * D * 4);
    float* hcat     = (float*)alloc((size_t)192 * 4);
    unsigned short* bufA  = (unsigned short*)alloc((size_t)Nn * S * D * 2);    // 41MB
    unsigned int*   tbl8  = (unsigned int*)alloc((size_t)Nn * D * 4);          // 20.5MB int8 table
    float*          tscal = (float*)alloc((size_t)Nn * 4 * 4);                 // 320KB float4 scales
    float* hgru     = (float*)alloc((size_t)Nn * D * 4);                       // 20.5MB
    unsigned short* hgru_bf = (unsigned short*)alloc((size_t)Nn * D * 2);      // 10.2MB
    unsigned short* f1cat = (unsigned short*)alloc((size_t)Nn * 192 * 2);      // 7.7MB
    unsigned short* f2    = (unsigned short*)alloc((size_t)Nn * 64 * 2);       // 2.6MB

    auto cdiv = [](int a, int b) { return (a + b - 1) / b; };

    // ---- graph + weight preprocessing ----
    init_deg_cnt_kernel<<<cdiv(Nn, 256), 256, 0, stream>>>(deg, cnt, Nn);
    deg_hist_kernel<<<cdiv(E, 256), 256, 0, stream>>>(edst, ew, deg, cnt, E);
    scan_rowptr_kernel<<<1, 1024, 0, stream>>>(cnt, rowptr, deg, dinv, selfnorm, Nn);
    csr_fill_kernel<<<cdiv(E, 256), 256, 0, stream>>>(esrc, edst, ew, dinv, rowptr, cnt, csrc, cnorm, E);
    convert_weights_kernel<<<cdiv(CW6, 256), 256, 0, stream>>>(
        gcn_W, Wih, Whh, fc1W, fc2W, dh1W, bih, bhh, fc1b, dh1b,
        Wtb, Wihb, Whhb, fc1dh1Wb, fc2Wb, gbias, hcat);

    // ---- batched GCN stack: all 4 snapshots at once; int8 gather table ----
    {
        dim3 g1(D / GBN, (Nn * S) / GBM);   // (2, 625)
        gemm_bt_bf16_kernel<3, 0, 1, 0><<<g1, 256, 0, stream>>>(
            (const unsigned short*)x, D, Wtb, nullptr, (unsigned short*)tbl8, tscal,
            nullptr, nullptr, nullptr, 0, Nn * S, D, D);
        gcn_agg_ln_relu4_kernel<<<Nn / 4, 256, 0, stream>>>(
            tbl8, (const float4*)tscal, rowptr, csrc, cnorm, selfnorm,
            gcn_b, ln_g, ln_b, bufA);
        for (int l = 1; l < L; ++l) {
            gemm_bt_bf16_kernel<3, 0, 0, 0><<<g1, 256, 0, stream>>>(
                bufA, D, Wtb + (size_t)l * D * D, nullptr, (unsigned short*)tbl8, tscal,
                nullptr, nullptr, nullptr, 0, Nn * S, D, D);
            gcn_agg_ln_relu4_kernel<<<Nn / 4, 256, 0, stream>>>(
                tbl8, (const float4*)tscal, rowptr, csrc, cnorm, selfnorm,
                gcn_b + (size_t)l * D, ln_g + (size_t)l * D, ln_b + (size_t)l * D, bufA);
        }
    }

    // ---- fused GRU loop (1 kernel per snapshot; s=0 skips the h-phase) ----
    for (int s = 0; s < S; ++s) {
        dim3 g2(D / 64, cdiv(Nn, 64));   // (4, 313)
        gru_fused_kernel<<<g2, 256, 0, stream>>>(
            bufA + (size_t)s * D, S * D, hgru_bf, Wihb, Whhb, gbias,
            hgru, hgru_bf, (s < S - 1) ? 1 : 0, (s == 0) ? 1 : 0);
    }

    // ---- heads: merged fc1+dh1 GEMM (+fused dh2 head), fc2 GEMM (+fused fc3 head)
    {
        dim3 gf1(2, cdiv(Nn, GBM));   // N=192 -> 2 col-blocks; cols 128-191 feed dh2
        gemm_bt_bf16_kernel<1, 1, 0, 1><<<gf1, 256, 0, stream>>>(
            hgru_bf, D, fc1dh1Wb, hcat, f1cat, nullptr,
            dh2W, dh2b, out + (size_t)Nn * H, 128, Nn, 192, 256);
        dim3 gf2(1, cdiv(Nn, GBM));   // N=64; cols 0-63 feed fc3
        gemm_bt_bf16_kernel<1, 1, 0, 1><<<gf2, 256, 0, stream>>>(
            f1cat, 192, fc2Wb, fc2b, f2, nullptr,
            fc3W, fc3b, out, 0, Nn, 64, 128);
    }
}

// Round 15
// 725.757 us; speedup vs baseline: 1.0372x; 1.0372x over previous
//
#include <hip/hip_runtime.h>
#include <hip/hip_bf16.h>

// Problem constants (from reference)
constexpr int Nn = 20000;   // nodes
constexpr int D  = 256;     // feature dim
constexpr int S  = 4;       // snapshots
constexpr int E  = 320000;  // edges
constexpr int H  = 5;       // horizon
constexpr int L  = 3;       // GCN layers

using bf16 = __hip_bfloat16;
typedef __attribute__((ext_vector_type(8))) short v8s;   // 8 bf16 = 4 VGPRs
typedef __attribute__((ext_vector_type(4))) float v4f;   // MFMA acc

#define GLOBAL_AS __attribute__((address_space(1)))
#define LDS_AS    __attribute__((address_space(3)))

__device__ __forceinline__ float gelu_exact(float x) {
    return 0.5f * x * (1.0f + erff(x * 0.70710678118654752440f));
}
__device__ __forceinline__ unsigned short f2bu(float f) {
    bf16 h = __float2bfloat16(f);
    return *reinterpret_cast<unsigned short*>(&h);
}
__device__ __forceinline__ float b2f(unsigned short u) {
    unsigned int v = (unsigned int)u << 16;
    return __uint_as_float(v);
}
// sign-extend byte k of packed uint -> float
__device__ __forceinline__ float sx0(unsigned int v) { return (float)((int)(v << 24) >> 24); }
__device__ __forceinline__ float sx1(unsigned int v) { return (float)((int)(v << 16) >> 24); }
__device__ __forceinline__ float sx2(unsigned int v) { return (float)((int)(v << 8) >> 24); }
__device__ __forceinline__ float sx3(unsigned int v) { return (float)((int)v >> 24); }

// ---------------- preprocessing kernels (parallel; scan stays lean) ----------------
__global__ void init_deg_cnt_kernel(float* deg, int* cnt, int n) {
    int i = blockIdx.x * blockDim.x + threadIdx.x;
    if (i < n) { deg[i] = 1.0f; cnt[i] = 0; }
}
__global__ void deg_hist_kernel(const int* __restrict__ dst, const float* __restrict__ w,
                                float* __restrict__ deg, int* __restrict__ cnt, int e) {
    int i = blockIdx.x * blockDim.x + threadIdx.x;
    if (i < e) {
        int d = dst[i];
        atomicAdd(&deg[d], w[i]);
        atomicAdd(&cnt[d], 1);
    }
}
__global__ void dinv_kernel(const float* __restrict__ deg, float* __restrict__ dinv,
                            float* __restrict__ selfnorm, int n) {
    int i = blockIdx.x * blockDim.x + threadIdx.x;
    if (i < n) {
        float dg = deg[i];
        float dv = dg > 0.0f ? rsqrtf(fmaxf(dg, 1e-5f)) : 0.0f;
        dinv[i] = dv;
        selfnorm[i] = dv * dv;
    }
}
// 1024-thread exclusive scan over cnt[0..n) -> rowptr[0..n]; zeroes cnt.
// NOTE (R14 post-mortem): do NOT fold per-node math in here — single block,
// one CU; fusing dinv made this 64.7 us at 0.12% occupancy.
__global__ __launch_bounds__(1024) void scan_rowptr_kernel(int* __restrict__ cnt,
                                                           int* __restrict__ rowptr, int n) {
    __shared__ int wsum[16];
    __shared__ int woff[16];
    int t = threadIdx.x;
    int wave = t >> 6, lane = t & 63;
    int chunk = (n + 1023) / 1024;
    int start = t * chunk;
    int end = start + chunk; if (end > n) end = n;
    int s = 0;
    for (int i = start; i < end; ++i) s += cnt[i];
    int incl = s;
#pragma unroll
    for (int off = 1; off < 64; off <<= 1) {
        int v = __shfl_up(incl, off);
        if (lane >= off) incl += v;
    }
    int excl = incl - s;
    if (lane == 63) wsum[wave] = incl;
    __syncthreads();
    if (t == 0) {
        int acc = 0;
        for (int i = 0; i < 16; ++i) { woff[i] = acc; acc += wsum[i]; }
        rowptr[n] = acc;
    }
    __syncthreads();
    int acc = woff[wave] + excl;
    for (int i = start; i < end; ++i) {
        rowptr[i] = acc; acc += cnt[i]; cnt[i] = 0;
    }
}
// fill CSR: csrc (src index) + cnorm (edge norm)
__global__ void csr_fill_kernel(const int* __restrict__ src, const int* __restrict__ dst,
                                const float* __restrict__ w, const float* __restrict__ dinv,
                                const int* __restrict__ rowptr,
                                int* __restrict__ cursor, int* __restrict__ csrc,
                                float* __restrict__ cnorm, int e) {
    int i = blockIdx.x * blockDim.x + threadIdx.x;
    if (i < e) {
        int sN = src[i], dN = dst[i];
        int pos = rowptr[dN] + atomicAdd(&cursor[dN], 1);
        csrc[pos] = sN;
        cnorm[pos] = dinv[sN] * w[i] * dinv[dN];
    }
}
// All weight conversions + GRU bias combine + head weight/bias concat.
constexpr int CW0 = L * D * D;          // gcn_W -> Wtb (transposed)
constexpr int CW1 = CW0 + 3 * D * D;    // Wih
constexpr int CW2 = CW1 + 3 * D * D;    // Whh
constexpr int CW3 = CW2 + 192 * 256;    // fc1W (rows 0-127) + dh1W (rows 128-191)
constexpr int CW4 = CW3 + 64 * 128;     // fc2W
constexpr int CW5 = CW4 + 4 * D;        // gbias: br, bz, big, bhg
constexpr int CW6 = CW5 + 192;          // hcat: fc1b | dh1b
__global__ void convert_weights_kernel(
    const float* __restrict__ gcn_W, const float* __restrict__ Wih,
    const float* __restrict__ Whh, const float* __restrict__ fc1W,
    const float* __restrict__ fc2W, const float* __restrict__ dh1W,
    const float* __restrict__ bih, const float* __restrict__ bhh,
    const float* __restrict__ fc1b, const float* __restrict__ dh1b,
    unsigned short* __restrict__ Wtb, unsigned short* __restrict__ Wihb,
    unsigned short* __restrict__ Whhb, unsigned short* __restrict__ fc1dh1Wb,
    unsigned short* __restrict__ fc2Wb,
    float* __restrict__ gbias, float* __restrict__ hcat)
{
    int i = blockIdx.x * blockDim.x + threadIdx.x;
    if (i < CW0) {
        int l = i / (D * D);
        int rem = i - l * D * D;
        int k = rem / D;
        int n = rem - k * D;
        Wtb[(size_t)l * D * D + (size_t)n * D + k] = f2bu(gcn_W[i]);
    } else if (i < CW1) { int j = i - CW0; Wihb[j] = f2bu(Wih[j]); }
    else if (i < CW2)   { int j = i - CW1; Whhb[j] = f2bu(Whh[j]); }
    else if (i < CW3) {
        int j = i - CW2;
        fc1dh1Wb[j] = (j < 128 * 256) ? f2bu(fc1W[j]) : f2bu(dh1W[j - 128 * 256]);
    }
    else if (i < CW4)   { int j = i - CW3; fc2Wb[j] = f2bu(fc2W[j]); }
    else if (i < CW5) {
        int j = i - CW4;           // 0..1023
        int g = j >> 8, d = j & 255;
        float v;
        if (g == 0)      v = bih[d] + bhh[d];            // br
        else if (g == 1) v = bih[D + d] + bhh[D + d];    // bz
        else if (g == 2) v = bih[2 * D + d];             // big
        else             v = bhh[2 * D + d];             // bhg
        gbias[j] = v;
    }
    else if (i < CW6) {
        int j = i - CW5;           // 0..191
        hcat[j] = (j < 128) ? fc1b[j] : dh1b[j - 128];
    }
}

// ---------------- bf16 MFMA GEMM: C = A[M,K](lda) * B[N,K]^T (+bias) -------------
// OUT_MODE 1: bf16 C[M,N] row-major (store-guarded; gelu if ACT).
// OUT_MODE 3: int8 gather table [node][dim][snap] + per-(node,64-dim-quarter)
//             absmax scale (Cscale[node*4+quarter]); rows gm=node*4+snap.
// XIN 1: A is f32 x [S][Nn][D]; row gm=(node*4+snap) -> x row snap*Nn+node.
// HFUSE 1: waves whose 64-col range == [headColBase, +64) also compute the
//          5-output head via in-quad shfl reduction (no separate head dispatch).
#define GBM 128
#define GBN 128
#define GBK 64
template<int OUT_MODE, int ACT, int XIN, int HFUSE>
__global__ __launch_bounds__(256) void gemm_bt_bf16_kernel(
    const unsigned short* __restrict__ A, int lda,
    const unsigned short* __restrict__ B,
    const float* __restrict__ bias, unsigned short* __restrict__ C,
    float* __restrict__ Cscale,
    const float* __restrict__ headW, const float* __restrict__ headb,
    float* __restrict__ headOut, int headColBase,
    int M, int N, int K)
{
    __shared__ short As[GBM * GBK];
    __shared__ short Bs[GBN * GBK];
    int tid = threadIdx.x;
    int wave = tid >> 6, lane = tid & 63;
    int ln = lane & 15, quad = lane >> 4;
    int wr = wave >> 1, wc = wave & 1;
    int bm = blockIdx.y * GBM, bn = blockIdx.x * GBN;

    v4f acc[4][4];
#pragma unroll
    for (int i = 0; i < 4; ++i)
#pragma unroll
        for (int j = 0; j < 4; ++j)
            acc[i][j] = (v4f)(0.0f);

    int lrow = lane >> 3;          // 0..7 within 8-row segment
    int lcol = (lane & 7) * 8;     // bf16 col offset, 16B chunks

    for (int k0 = 0; k0 < K; k0 += GBK) {
#pragma unroll
        for (int c = 0; c < 4; ++c) {
            int seg = wave * 4 + c;           // 0..15
            int row = seg * 8 + lrow;         // 0..127
            int gm = bm + row; if (gm >= M) gm = M - 1;   // clamp: dup rows, never stored
            if (XIN) {
                int xr = (gm & 3) * Nn + (gm >> 2);
                const float* xp = (const float*)A + (size_t)xr * D + k0 + lcol;
                float4 v0 = *(const float4*)xp;
                float4 v1 = *(const float4*)(xp + 4);
                v8s o;
                o[0] = (short)f2bu(v0.x); o[1] = (short)f2bu(v0.y);
                o[2] = (short)f2bu(v0.z); o[3] = (short)f2bu(v0.w);
                o[4] = (short)f2bu(v1.x); o[5] = (short)f2bu(v1.y);
                o[6] = (short)f2bu(v1.z); o[7] = (short)f2bu(v1.w);
                *(v8s*)(&As[row * GBK + lcol]) = o;
            } else {
                __builtin_amdgcn_global_load_lds(
                    (const GLOBAL_AS unsigned int*)(A + (size_t)gm * lda + k0 + lcol),
                    (LDS_AS unsigned int*)(&As[row * GBK + lcol]), 16, 0, 0);
            }
            int gn = bn + row; if (gn >= N) gn = N - 1;   // clamp for N<128 col-blocks
            __builtin_amdgcn_global_load_lds(
                (const GLOBAL_AS unsigned int*)(B + (size_t)gn * K + k0 + lcol),
                (LDS_AS unsigned int*)(&Bs[row * GBK + lcol]), 16, 0, 0);
        }
        __syncthreads();
#pragma unroll
        for (int ks = 0; ks < 2; ++ks) {
            v8s af[4], bfr[4];
#pragma unroll
            for (int i = 0; i < 4; ++i) {
                int row = wr * 64 + i * 16 + ln;
                af[i] = *(const v8s*)(&As[row * GBK + ks * 32 + quad * 8]);
            }
#pragma unroll
            for (int j = 0; j < 4; ++j) {
                int row = wc * 64 + j * 16 + ln;
                bfr[j] = *(const v8s*)(&Bs[row * GBK + ks * 32 + quad * 8]);
            }
#pragma unroll
            for (int i = 0; i < 4; ++i)
#pragma unroll
                for (int j = 0; j < 4; ++j)
                    acc[i][j] = __builtin_amdgcn_mfma_f32_16x16x32_bf16(af[i], bfr[j], acc[i][j], 0, 0, 0);
        }
        __syncthreads();
    }
    // epilogue: C/D layout col=lane&15, row=quad*4+reg
    if (OUT_MODE == 3) {
#pragma unroll
        for (int i = 0; i < 4; ++i) {
            int gmb = bm + wr * 64 + i * 16 + quad * 4;
            int node = gmb >> 2;
            float mx = 0.0f;
#pragma unroll
            for (int j = 0; j < 4; ++j)
#pragma unroll
                for (int r = 0; r < 4; ++r)
                    mx = fmaxf(mx, fabsf(acc[i][j][r]));
            mx = fmaxf(mx, __shfl_xor(mx, 1));
            mx = fmaxf(mx, __shfl_xor(mx, 2));
            mx = fmaxf(mx, __shfl_xor(mx, 4));
            mx = fmaxf(mx, __shfl_xor(mx, 8));
            float inv = mx > 0.0f ? 127.0f / mx : 0.0f;
#pragma unroll
            for (int j = 0; j < 4; ++j) {
                int gn = bn + wc * 64 + j * 16 + ln;
                int q0 = (int)lrintf(fminf(fmaxf(acc[i][j][0] * inv, -127.0f), 127.0f));
                int q1 = (int)lrintf(fminf(fmaxf(acc[i][j][1] * inv, -127.0f), 127.0f));
                int q2 = (int)lrintf(fminf(fmaxf(acc[i][j][2] * inv, -127.0f), 127.0f));
                int q3 = (int)lrintf(fminf(fmaxf(acc[i][j][3] * inv, -127.0f), 127.0f));
                unsigned int pk = (q0 & 0xff) | ((q1 & 0xff) << 8)
                                | ((q2 & 0xff) << 16) | ((q3 & 0xff) << 24);
                ((unsigned int*)C)[(size_t)node * D + gn] = pk;
            }
            if (ln == 0) {
                int quarter = (bn >> 6) + wc;
                Cscale[(size_t)node * 4 + quarter] = mx * (1.0f / 127.0f);
            }
        }
    } else {
#pragma unroll
        for (int i = 0; i < 4; ++i) {
            int gmb = bm + wr * 64 + i * 16 + quad * 4;
#pragma unroll
            for (int j = 0; j < 4; ++j) {
                int gn = bn + wc * 64 + j * 16 + ln;
                float bv = (bias && gn < N) ? bias[gn] : 0.0f;
                if (gn < N) {
#pragma unroll
                    for (int r = 0; r < 4; ++r) {
                        int gm = gmb + r;
                        if (gm < M) {
                            float v = acc[i][j][r] + bv;
                            if (ACT == 1) v = gelu_exact(v);
                            C[(size_t)gm * N + gn] = f2bu(v);
                        }
                    }
                }
            }
        }
        if (HFUSE && (bn + wc * 64 == headColBase)) {
            // this wave's 64x64 tile feeds the 5-output head
#pragma unroll
            for (int i = 0; i < 4; ++i) {
                float ph[4][5];
#pragma unroll
                for (int r = 0; r < 4; ++r)
#pragma unroll
                    for (int h = 0; h < 5; ++h) ph[r][h] = 0.0f;
#pragma unroll
                for (int j = 0; j < 4; ++j) {
                    int kcol = j * 16 + ln;
                    int gn = headColBase + kcol;
                    float bv = bias ? bias[gn] : 0.0f;
                    float w0 = headW[0 * 64 + kcol];
                    float w1 = headW[1 * 64 + kcol];
                    float w2 = headW[2 * 64 + kcol];
                    float w3 = headW[3 * 64 + kcol];
                    float w4 = headW[4 * 64 + kcol];
#pragma unroll
                    for (int r = 0; r < 4; ++r) {
                        float v = acc[i][j][r] + bv;
                        if (ACT == 1) v = gelu_exact(v);
                        ph[r][0] = fmaf(v, w0, ph[r][0]);
                        ph[r][1] = fmaf(v, w1, ph[r][1]);
                        ph[r][2] = fmaf(v, w2, ph[r][2]);
                        ph[r][3] = fmaf(v, w3, ph[r][3]);
                        ph[r][4] = fmaf(v, w4, ph[r][4]);
                    }
                }
#pragma unroll
                for (int off = 1; off < 16; off <<= 1)
#pragma unroll
                    for (int r = 0; r < 4; ++r)
#pragma unroll
                        for (int h = 0; h < 5; ++h)
                            ph[r][h] += __shfl_xor(ph[r][h], off);
                if (ln == 0) {
                    int gmb = bm + wr * 64 + i * 16 + quad * 4;
#pragma unroll
                    for (int r = 0; r < 4; ++r) {
                        int gm = gmb + r;
                        if (gm < M) {
#pragma unroll
                            for (int h = 0; h < 5; ++h)
                                headOut[(size_t)gm * H + h] = ph[r][h] + headb[h];
                        }
                    }
                }
            }
        }
    }
}

// ---------------- fused GRU step: both GEMMs + gates in one kernel ----------------
__global__ __launch_bounds__(256) void gru_fused_kernel(
    const unsigned short* __restrict__ feat, int fstride,   // phase-0 A
    const unsigned short* __restrict__ hbf,                 // phase-1 A  [node][D]
    const unsigned short* __restrict__ Wihb,                // [3*D][D]
    const unsigned short* __restrict__ Whhb,
    const float* __restrict__ gbias,                        // [4*D] br,bz,big,bhg
    float* __restrict__ h, unsigned short* __restrict__ hb,
    int write_f32, int first)
{
    __shared__ short As[64 * 64];     // 8 KB
    __shared__ short Bs[192 * 64];    // 24 KB (3 gates x 64 dims)
    int tid = threadIdx.x;
    int wave = tid >> 6, lane = tid & 63;
    int ln = lane & 15, quad = lane >> 4;
    int wm = wave >> 1, wn = wave & 1;
    int bm = blockIdx.y * 64;
    int bn = blockIdx.x * 64;        // dim block

    v4f accR[2][2], accZ[2][2], accG[2][2], accHG[2][2];
#pragma unroll
    for (int mi = 0; mi < 2; ++mi)
#pragma unroll
        for (int nj = 0; nj < 2; ++nj) {
            accR[mi][nj] = (v4f)(0.0f); accZ[mi][nj] = (v4f)(0.0f);
            accG[mi][nj] = (v4f)(0.0f); accHG[mi][nj] = (v4f)(0.0f);
        }

    int lrow = lane >> 3, lcol = (lane & 7) * 8;
    int nphase = first ? 1 : 2;

    for (int phase = 0; phase < nphase; ++phase) {
        const unsigned short* A = phase ? hbf : feat;
        int astr = phase ? D : fstride;
        const unsigned short* W = phase ? Whhb : Wihb;
        for (int k0 = 0; k0 < D; k0 += 64) {
#pragma unroll
            for (int c = 0; c < 2; ++c) {
                int row = wave * 16 + c * 8 + lrow;
                int gm = bm + row; if (gm >= Nn) gm = Nn - 1;
                __builtin_amdgcn_global_load_lds(
                    (const GLOBAL_AS unsigned int*)(A + (size_t)gm * astr + k0 + lcol),
                    (LDS_AS unsigned int*)(&As[row * 64 + lcol]), 16, 0, 0);
            }
#pragma unroll
            for (int c = 0; c < 6; ++c) {
                int row = wave * 48 + c * 8 + lrow;   // 0..191
                int g = row >> 6, dloc = row & 63;
                __builtin_amdgcn_global_load_lds(
                    (const GLOBAL_AS unsigned int*)(W + ((size_t)(g * D + bn + dloc)) * D + k0 + lcol),
                    (LDS_AS unsigned int*)(&Bs[row * 64 + lcol]), 16, 0, 0);
            }
            __syncthreads();
#pragma unroll
            for (int ks = 0; ks < 2; ++ks) {
                v8s am[2];
#pragma unroll
                for (int mi = 0; mi < 2; ++mi)
                    am[mi] = *(const v8s*)(&As[(wm * 32 + mi * 16 + ln) * 64 + ks * 32 + quad * 8]);
#pragma unroll
                for (int g = 0; g < 3; ++g) {
#pragma unroll
                    for (int nj = 0; nj < 2; ++nj) {
                        v8s bf = *(const v8s*)(&Bs[(g * 64 + wn * 32 + nj * 16 + ln) * 64 + ks * 32 + quad * 8]);
#pragma unroll
                        for (int mi = 0; mi < 2; ++mi) {
                            if (g == 0)
                                accR[mi][nj] = __builtin_amdgcn_mfma_f32_16x16x32_bf16(am[mi], bf, accR[mi][nj], 0, 0, 0);
                            else if (g == 1)
                                accZ[mi][nj] = __builtin_amdgcn_mfma_f32_16x16x32_bf16(am[mi], bf, accZ[mi][nj], 0, 0, 0);
                            else if (phase == 0)
                                accG[mi][nj] = __builtin_amdgcn_mfma_f32_16x16x32_bf16(am[mi], bf, accG[mi][nj], 0, 0, 0);
                            else
                                accHG[mi][nj] = __builtin_amdgcn_mfma_f32_16x16x32_bf16(am[mi], bf, accHG[mi][nj], 0, 0, 0);
                        }
                    }
                }
            }
            __syncthreads();
        }
    }
#pragma unroll
    for (int mi = 0; mi < 2; ++mi) {
        int gm0 = bm + wm * 32 + mi * 16 + quad * 4;
#pragma unroll
        for (int nj = 0; nj < 2; ++nj) {
            int gn = bn + wn * 32 + nj * 16 + ln;
            float vbr = gbias[gn], vbz = gbias[D + gn];
            float vbig = gbias[2 * D + gn], vbhg = gbias[3 * D + gn];
#pragma unroll
            for (int r = 0; r < 4; ++r) {
                int gm = gm0 + r;
                if (gm < Nn) {
                    float rv = 1.0f / (1.0f + expf(-(accR[mi][nj][r] + vbr)));
                    float zv = 1.0f / (1.0f + expf(-(accZ[mi][nj][r] + vbz)));
                    float nv = tanhf(accG[mi][nj][r] + vbig + rv * (accHG[mi][nj][r] + vbhg));
                    float hold = first ? 0.0f : h[(size_t)gm * D + gn];
                    float hv = (1.0f - zv) * nv + zv * hold;
                    if (write_f32) h[(size_t)gm * D + gn] = hv;
                    hb[(size_t)gm * D + gn] = f2bu(hv);
                }
            }
        }
    }
}

// ------- GCN aggregate (4 snapshots, int8 table) + bias + LN + ReLU, wave/node ----
__global__ __launch_bounds__(256) void gcn_agg_ln_relu4_kernel(
    const unsigned int* __restrict__ tbl8, const float4* __restrict__ scales,
    const int* __restrict__ rowptr,
    const int* __restrict__ csrc, const float* __restrict__ cnorm,
    const float* __restrict__ selfnorm,
    const float* __restrict__ gcn_b, const float* __restrict__ ln_g,
    const float* __restrict__ ln_b, unsigned short* __restrict__ out)
{
    int wave = threadIdx.x >> 6, lane = threadIdx.x & 63;
    int i = blockIdx.x * 4 + wave;

    float acc[4][4];   // [q dim-seg][s snap]
    {
        float w = selfnorm[i];
        float4 sc = scales[i];
        float wq[4] = {w * sc.x, w * sc.y, w * sc.z, w * sc.w};
#pragma unroll
        for (int q = 0; q < 4; ++q) {
            unsigned int v = tbl8[(size_t)i * D + lane + q * 64];
            acc[q][0] = wq[q] * sx0(v); acc[q][1] = wq[q] * sx1(v);
            acc[q][2] = wq[q] * sx2(v); acc[q][3] = wq[q] * sx3(v);
        }
    }
    int beg = rowptr[i], end = rowptr[i + 1];
    int p = beg;
    for (; p + 1 < end; p += 2) {
        int sA = csrc[p], sB = csrc[p + 1];
        float wA = cnorm[p], wB = cnorm[p + 1];
        float4 scA = scales[sA], scB = scales[sB];
        unsigned int uA[4], uB[4];
#pragma unroll
        for (int q = 0; q < 4; ++q) {
            uA[q] = tbl8[(size_t)sA * D + lane + q * 64];
            uB[q] = tbl8[(size_t)sB * D + lane + q * 64];
        }
        float wqA[4] = {wA * scA.x, wA * scA.y, wA * scA.z, wA * scA.w};
        float wqB[4] = {wB * scB.x, wB * scB.y, wB * scB.z, wB * scB.w};
#pragma unroll
        for (int q = 0; q < 4; ++q) {
            acc[q][0] = fmaf(wqA[q], sx0(uA[q]), acc[q][0]);
            acc[q][1] = fmaf(wqA[q], sx1(uA[q]), acc[q][1]);
            acc[q][2] = fmaf(wqA[q], sx2(uA[q]), acc[q][2]);
            acc[q][3] = fmaf(wqA[q], sx3(uA[q]), acc[q][3]);
            acc[q][0] = fmaf(wqB[q], sx0(uB[q]), acc[q][0]);
            acc[q][1] = fmaf(wqB[q], sx1(uB[q]), acc[q][1]);
            acc[q][2] = fmaf(wqB[q], sx2(uB[q]), acc[q][2]);
            acc[q][3] = fmaf(wqB[q], sx3(uB[q]), acc[q][3]);
        }
    }
    if (p < end) {
        int sA = csrc[p]; float wA = cnorm[p];
        float4 scA = scales[sA];
        float wqA[4] = {wA * scA.x, wA * scA.y, wA * scA.z, wA * scA.w};
#pragma unroll
        for (int q = 0; q < 4; ++q) {
            unsigned int v = tbl8[(size_t)sA * D + lane + q * 64];
            acc[q][0] = fmaf(wqA[q], sx0(v), acc[q][0]);
            acc[q][1] = fmaf(wqA[q], sx1(v), acc[q][1]);
            acc[q][2] = fmaf(wqA[q], sx2(v), acc[q][2]);
            acc[q][3] = fmaf(wqA[q], sx3(v), acc[q][3]);
        }
    }
#pragma unroll
    for (int q = 0; q < 4; ++q) {
        float bb = gcn_b[lane + q * 64];
        acc[q][0] += bb; acc[q][1] += bb; acc[q][2] += bb; acc[q][3] += bb;
    }
    float s1[4], s2[4];
#pragma unroll
    for (int s = 0; s < 4; ++s) {
        s1[s] = acc[0][s] + acc[1][s] + acc[2][s] + acc[3][s];
        s2[s] = acc[0][s] * acc[0][s] + acc[1][s] * acc[1][s]
              + acc[2][s] * acc[2][s] + acc[3][s] * acc[3][s];
    }
#pragma unroll
    for (int off = 32; off > 0; off >>= 1) {
#pragma unroll
        for (int s = 0; s < 4; ++s) {
            s1[s] += __shfl_xor(s1[s], off);
            s2[s] += __shfl_xor(s2[s], off);
        }
    }
    const float inv = 1.0f / D;
    float m[4], rr[4];
#pragma unroll
    for (int s = 0; s < 4; ++s) {
        m[s] = s1[s] * inv;
        rr[s] = rsqrtf(s2[s] * inv - m[s] * m[s] + 1e-5f);
    }
    size_t ob = (size_t)(i << 2) * D;
#pragma unroll
    for (int q = 0; q < 4; ++q) {
        int d = lane + q * 64;
        float g = ln_g[d], lb = ln_b[d];
#pragma unroll
        for (int s = 0; s < 4; ++s) {
            float y = (acc[q][s] - m[s]) * rr[s] * g + lb;
            out[ob + (size_t)s * D + d] = f2bu(fmaxf(y, 0.0f));
        }
    }
}

extern "C" void kernel_launch(void* const* d_in, const int* in_sizes, int n_in,
                              void* d_out, int out_size, void* d_ws, size_t ws_size,
                              hipStream_t stream)
{
    const float* x     = (const float*)d_in[0];
    const int*   esrc  = (const int*)d_in[1];
    const int*   edst  = (const int*)d_in[2];
    const float* ew    = (const float*)d_in[3];
    const float* gcn_W = (const float*)d_in[4];
    const float* gcn_b = (const float*)d_in[5];
    const float* ln_g  = (const float*)d_in[6];
    const float* ln_b  = (const float*)d_in[7];
    const float* Wih   = (const float*)d_in[8];
    const float* Whh   = (const float*)d_in[9];
    const float* bih   = (const float*)d_in[10];
    const float* bhh   = (const float*)d_in[11];
    const float* fc1W  = (const float*)d_in[12];
    const float* fc1b  = (const float*)d_in[13];
    const float* fc2W  = (const float*)d_in[14];
    const float* fc2b  = (const float*)d_in[15];
    const float* fc3W  = (const float*)d_in[16];
    const float* fc3b  = (const float*)d_in[17];
    const float* dh1W  = (const float*)d_in[18];
    const float* dh1b  = (const float*)d_in[19];
    const float* dh2W  = (const float*)d_in[20];
    const float* dh2b  = (const float*)d_in[21];

    float* out = (float*)d_out;   // [Nn*H forecast][Nn*H direction]

    // workspace carve-out (aligned to 256B); total ~111 MB
    char* p = (char*)d_ws;
    auto alloc = [&](size_t bytes) -> void* {
        void* r = (void*)p;
        p += (bytes + 255) & ~(size_t)255;
        return r;
    };
    float* deg      = (float*)alloc((size_t)Nn * 4);
    float* dinv     = (float*)alloc((size_t)Nn * 4);
    float* selfnorm = (float*)alloc((size_t)Nn * 4);
    int*   rowptr   = (int*)alloc((size_t)(Nn + 1) * 4);
    int*   cnt      = (int*)alloc((size_t)Nn * 4);
    int*   csrc     = (int*)alloc((size_t)E * 4);
    float* cnorm    = (float*)alloc((size_t)E * 4);
    unsigned short* Wtb      = (unsigned short*)alloc((size_t)L * D * D * 2);
    unsigned short* Wihb     = (unsigned short*)alloc((size_t)3 * D * D * 2);
    unsigned short* Whhb     = (unsigned short*)alloc((size_t)3 * D * D * 2);
    unsigned short* fc1dh1Wb = (unsigned short*)alloc((size_t)192 * 256 * 2);
    unsigned short* fc2Wb    = (unsigned short*)alloc((size_t)64 * 128 * 2);
    float* gbias    = (float*)alloc((size_t)4 * D * 4);
    float* hcat     = (float*)alloc((size_t)192 * 4);
    unsigned short* bufA  = (unsigned short*)alloc((size_t)Nn * S * D * 2);    // 41MB
    unsigned int*   tbl8  = (unsigned int*)alloc((size_t)Nn * D * 4);          // 20.5MB int8 table
    float*          tscal = (float*)alloc((size_t)Nn * 4 * 4);                 // 320KB float4 scales
    float* hgru     = (float*)alloc((size_t)Nn * D * 4);                       // 20.5MB
    unsigned short* hgru_bf = (unsigned short*)alloc((size_t)Nn * D * 2);      // 10.2MB
    unsigned short* f1cat = (unsigned short*)alloc((size_t)Nn * 192 * 2);      // 7.7MB
    unsigned short* f2    = (unsigned short*)alloc((size_t)Nn * 64 * 2);       // 2.6MB

    auto cdiv = [](int a, int b) { return (a + b - 1) / b; };

    // ---- graph + weight preprocessing ----
    init_deg_cnt_kernel<<<cdiv(Nn, 256), 256, 0, stream>>>(deg, cnt, Nn);
    deg_hist_kernel<<<cdiv(E, 256), 256, 0, stream>>>(edst, ew, deg, cnt, E);
    dinv_kernel<<<cdiv(Nn, 256), 256, 0, stream>>>(deg, dinv, selfnorm, Nn);
    scan_rowptr_kernel<<<1, 1024, 0, stream>>>(cnt, rowptr, Nn);
    csr_fill_kernel<<<cdiv(E, 256), 256, 0, stream>>>(esrc, edst, ew, dinv, rowptr, cnt, csrc, cnorm, E);
    convert_weights_kernel<<<cdiv(CW6, 256), 256, 0, stream>>>(
        gcn_W, Wih, Whh, fc1W, fc2W, dh1W, bih, bhh, fc1b, dh1b,
        Wtb, Wihb, Whhb, fc1dh1Wb, fc2Wb, gbias, hcat);

    // ---- batched GCN stack: all 4 snapshots at once; int8 gather table ----
    {
        dim3 g1(D / GBN, (Nn * S) / GBM);   // (2, 625)
        gemm_bt_bf16_kernel<3, 0, 1, 0><<<g1, 256, 0, stream>>>(
            (const unsigned short*)x, D, Wtb, nullptr, (unsigned short*)tbl8, tscal,
            nullptr, nullptr, nullptr, 0, Nn * S, D, D);
        gcn_agg_ln_relu4_kernel<<<Nn / 4, 256, 0, stream>>>(
            tbl8, (const float4*)tscal, rowptr, csrc, cnorm, selfnorm,
            gcn_b, ln_g, ln_b, bufA);
        for (int l = 1; l < L; ++l) {
            gemm_bt_bf16_kernel<3, 0, 0, 0><<<g1, 256, 0, stream>>>(
                bufA, D, Wtb + (size_t)l * D * D, nullptr, (unsigned short*)tbl8, tscal,
                nullptr, nullptr, nullptr, 0, Nn * S, D, D);
            gcn_agg_ln_relu4_kernel<<<Nn / 4, 256, 0, stream>>>(
                tbl8, (const float4*)tscal, rowptr, csrc, cnorm, selfnorm,
                gcn_b + (size_t)l * D, ln_g + (size_t)l * D, ln_b + (size_t)l * D, bufA);
        }
    }

    // ---- fused GRU loop (1 kernel per snapshot; s=0 skips the h-phase) ----
    for (int s = 0; s < S; ++s) {
        dim3 g2(D / 64, cdiv(Nn, 64));   // (4, 313)
        gru_fused_kernel<<<g2, 256, 0, stream>>>(
            bufA + (size_t)s * D, S * D, hgru_bf, Wihb, Whhb, gbias,
            hgru, hgru_bf, (s < S - 1) ? 1 : 0, (s == 0) ? 1 : 0);
    }

    // ---- heads: merged fc1+dh1 GEMM (+fused dh2 head), fc2 GEMM (+fused fc3 head)
    {
        dim3 gf1(2, cdiv(Nn, GBM));   // N=192 -> 2 col-blocks; cols 128-191 feed dh2
        gemm_bt_bf16_kernel<1, 1, 0, 1><<<gf1, 256, 0, stream>>>(
            hgru_bf, D, fc1dh1Wb, hcat, f1cat, nullptr,
            dh2W, dh2b, out + (size_t)Nn * H, 128, Nn, 192, 256);
        dim3 gf2(1, cdiv(Nn, GBM));   // N=64; cols 0-63 feed fc3
        gemm_bt_bf16_kernel<1, 1, 0, 1><<<gf2, 256, 0, stream>>>(
            f1cat, 192, fc2Wb, fc2b, f2, nullptr,
            fc3W, fc3b, out, 0, Nn, 64, 128);
    }
}

// Round 16
// 705.755 us; speedup vs baseline: 1.0666x; 1.0283x over previous
//
#include <hip/hip_runtime.h>
#include <hip/hip_bf16.h>

// Problem constants (from reference)
constexpr int Nn = 20000;   // nodes
constexpr int D  = 256;     // feature dim
constexpr int S  = 4;       // snapshots
constexpr int E  = 320000;  // edges
constexpr int H  = 5;       // horizon
constexpr int L  = 3;       // GCN layers

using bf16 = __hip_bfloat16;
typedef __attribute__((ext_vector_type(8))) short v8s;   // 8 bf16 = 4 VGPRs
typedef __attribute__((ext_vector_type(4))) float v4f;   // MFMA acc

#define GLOBAL_AS __attribute__((address_space(1)))
#define LDS_AS    __attribute__((address_space(3)))

__device__ __forceinline__ float gelu_exact(float x) {
    return 0.5f * x * (1.0f + erff(x * 0.70710678118654752440f));
}
__device__ __forceinline__ unsigned short f2bu(float f) {
    bf16 h = __float2bfloat16(f);
    return *reinterpret_cast<unsigned short*>(&h);
}
__device__ __forceinline__ float b2f(unsigned short u) {
    unsigned int v = (unsigned int)u << 16;
    return __uint_as_float(v);
}
// sign-extend byte k of packed uint -> float
__device__ __forceinline__ float sx0(unsigned int v) { return (float)((int)(v << 24) >> 24); }
__device__ __forceinline__ float sx1(unsigned int v) { return (float)((int)(v << 16) >> 24); }
__device__ __forceinline__ float sx2(unsigned int v) { return (float)((int)(v << 8) >> 24); }
__device__ __forceinline__ float sx3(unsigned int v) { return (float)((int)v >> 24); }

// ---------------- preprocessing kernels (parallel; scan stays lean) ----------------
__global__ void init_deg_cnt_kernel(float* deg, int* cnt, int n) {
    int i = blockIdx.x * blockDim.x + threadIdx.x;
    if (i < n) { deg[i] = 1.0f; cnt[i] = 0; }
}
__global__ void deg_hist_kernel(const int* __restrict__ dst, const float* __restrict__ w,
                                float* __restrict__ deg, int* __restrict__ cnt, int e) {
    int i = blockIdx.x * blockDim.x + threadIdx.x;
    if (i < e) {
        int d = dst[i];
        atomicAdd(&deg[d], w[i]);
        atomicAdd(&cnt[d], 1);
    }
}
__global__ void dinv_kernel(const float* __restrict__ deg, float* __restrict__ dinv,
                            float* __restrict__ selfnorm, int n) {
    int i = blockIdx.x * blockDim.x + threadIdx.x;
    if (i < n) {
        float dg = deg[i];
        float dv = dg > 0.0f ? rsqrtf(fmaxf(dg, 1e-5f)) : 0.0f;
        dinv[i] = dv;
        selfnorm[i] = dv * dv;
    }
}
// 1024-thread exclusive scan over cnt[0..n) -> rowptr[0..n]; zeroes cnt.
// NOTE (R14 post-mortem): keep this kernel LEAN — it's a single block on one
// CU; folding per-node math here cost 50 us at 0.12% occupancy.
__global__ __launch_bounds__(1024) void scan_rowptr_kernel(int* __restrict__ cnt,
                                                           int* __restrict__ rowptr, int n) {
    __shared__ int wsum[16];
    __shared__ int woff[16];
    int t = threadIdx.x;
    int wave = t >> 6, lane = t & 63;
    int chunk = (n + 1023) / 1024;
    int start = t * chunk;
    int end = start + chunk; if (end > n) end = n;
    int s = 0;
    for (int i = start; i < end; ++i) s += cnt[i];
    int incl = s;
#pragma unroll
    for (int off = 1; off < 64; off <<= 1) {
        int v = __shfl_up(incl, off);
        if (lane >= off) incl += v;
    }
    int excl = incl - s;
    if (lane == 63) wsum[wave] = incl;
    __syncthreads();
    if (t == 0) {
        int acc = 0;
        for (int i = 0; i < 16; ++i) { woff[i] = acc; acc += wsum[i]; }
        rowptr[n] = acc;
    }
    __syncthreads();
    int acc = woff[wave] + excl;
    for (int i = start; i < end; ++i) {
        rowptr[i] = acc; acc += cnt[i]; cnt[i] = 0;
    }
}
// fill CSR: csrc (src index) + cnorm (edge norm)
__global__ void csr_fill_kernel(const int* __restrict__ src, const int* __restrict__ dst,
                                const float* __restrict__ w, const float* __restrict__ dinv,
                                const int* __restrict__ rowptr,
                                int* __restrict__ cursor, int* __restrict__ csrc,
                                float* __restrict__ cnorm, int e) {
    int i = blockIdx.x * blockDim.x + threadIdx.x;
    if (i < e) {
        int sN = src[i], dN = dst[i];
        int pos = rowptr[dN] + atomicAdd(&cursor[dN], 1);
        csrc[pos] = sN;
        cnorm[pos] = dinv[sN] * w[i] * dinv[dN];
    }
}
// All weight conversions + GRU bias combine + head weight/bias concat.
constexpr int CW0 = L * D * D;          // gcn_W -> Wtb (transposed)
constexpr int CW1 = CW0 + 3 * D * D;    // Wih
constexpr int CW2 = CW1 + 3 * D * D;    // Whh
constexpr int CW3 = CW2 + 192 * 256;    // fc1W (rows 0-127) + dh1W (rows 128-191)
constexpr int CW4 = CW3 + 64 * 128;     // fc2W
constexpr int CW5 = CW4 + 4 * D;        // gbias: br, bz, big, bhg
constexpr int CW6 = CW5 + 192;          // hcat: fc1b | dh1b
__global__ void convert_weights_kernel(
    const float* __restrict__ gcn_W, const float* __restrict__ Wih,
    const float* __restrict__ Whh, const float* __restrict__ fc1W,
    const float* __restrict__ fc2W, const float* __restrict__ dh1W,
    const float* __restrict__ bih, const float* __restrict__ bhh,
    const float* __restrict__ fc1b, const float* __restrict__ dh1b,
    unsigned short* __restrict__ Wtb, unsigned short* __restrict__ Wihb,
    unsigned short* __restrict__ Whhb, unsigned short* __restrict__ fc1dh1Wb,
    unsigned short* __restrict__ fc2Wb,
    float* __restrict__ gbias, float* __restrict__ hcat)
{
    int i = blockIdx.x * blockDim.x + threadIdx.x;
    if (i < CW0) {
        int l = i / (D * D);
        int rem = i - l * D * D;
        int k = rem / D;
        int n = rem - k * D;
        Wtb[(size_t)l * D * D + (size_t)n * D + k] = f2bu(gcn_W[i]);
    } else if (i < CW1) { int j = i - CW0; Wihb[j] = f2bu(Wih[j]); }
    else if (i < CW2)   { int j = i - CW1; Whhb[j] = f2bu(Whh[j]); }
    else if (i < CW3) {
        int j = i - CW2;
        fc1dh1Wb[j] = (j < 128 * 256) ? f2bu(fc1W[j]) : f2bu(dh1W[j - 128 * 256]);
    }
    else if (i < CW4)   { int j = i - CW3; fc2Wb[j] = f2bu(fc2W[j]); }
    else if (i < CW5) {
        int j = i - CW4;           // 0..1023
        int g = j >> 8, d = j & 255;
        float v;
        if (g == 0)      v = bih[d] + bhh[d];            // br
        else if (g == 1) v = bih[D + d] + bhh[D + d];    // bz
        else if (g == 2) v = bih[2 * D + d];             // big
        else             v = bhh[2 * D + d];             // bhg
        gbias[j] = v;
    }
    else if (i < CW6) {
        int j = i - CW5;           // 0..191
        hcat[j] = (j < 128) ? fc1b[j] : dh1b[j - 128];
    }
}

// ---------------- bf16 MFMA GEMM: C = A[M,K](lda) * B[N,K]^T (+bias) -------------
// OUT_MODE 1: bf16 C[M,N] row-major (store-guarded; gelu if ACT).
// OUT_MODE 3: int8 gather table [node][dim][snap] + per-(node,64-dim-quarter)
//             absmax scale (Cscale[node*4+quarter]); rows gm=node*4+snap.
// XIN 1: A is f32 x [S][Nn][D]; row gm=(node*4+snap) -> x row snap*Nn+node.
#define GBM 128
#define GBN 128
#define GBK 64
template<int OUT_MODE, int ACT, int XIN>
__global__ __launch_bounds__(256) void gemm_bt_bf16_kernel(
    const unsigned short* __restrict__ A, int lda,
    const unsigned short* __restrict__ B,
    const float* __restrict__ bias, unsigned short* __restrict__ C,
    float* __restrict__ Cscale,
    int M, int N, int K)
{
    __shared__ short As[GBM * GBK];
    __shared__ short Bs[GBN * GBK];
    int tid = threadIdx.x;
    int wave = tid >> 6, lane = tid & 63;
    int ln = lane & 15, quad = lane >> 4;
    int wr = wave >> 1, wc = wave & 1;
    int bm = blockIdx.y * GBM, bn = blockIdx.x * GBN;

    v4f acc[4][4];
#pragma unroll
    for (int i = 0; i < 4; ++i)
#pragma unroll
        for (int j = 0; j < 4; ++j)
            acc[i][j] = (v4f)(0.0f);

    int lrow = lane >> 3;          // 0..7 within 8-row segment
    int lcol = (lane & 7) * 8;     // bf16 col offset, 16B chunks

    for (int k0 = 0; k0 < K; k0 += GBK) {
#pragma unroll
        for (int c = 0; c < 4; ++c) {
            int seg = wave * 4 + c;           // 0..15
            int row = seg * 8 + lrow;         // 0..127
            int gm = bm + row; if (gm >= M) gm = M - 1;   // clamp: dup rows, never stored
            if (XIN) {
                int xr = (gm & 3) * Nn + (gm >> 2);
                const float* xp = (const float*)A + (size_t)xr * D + k0 + lcol;
                float4 v0 = *(const float4*)xp;
                float4 v1 = *(const float4*)(xp + 4);
                v8s o;
                o[0] = (short)f2bu(v0.x); o[1] = (short)f2bu(v0.y);
                o[2] = (short)f2bu(v0.z); o[3] = (short)f2bu(v0.w);
                o[4] = (short)f2bu(v1.x); o[5] = (short)f2bu(v1.y);
                o[6] = (short)f2bu(v1.z); o[7] = (short)f2bu(v1.w);
                *(v8s*)(&As[row * GBK + lcol]) = o;
            } else {
                __builtin_amdgcn_global_load_lds(
                    (const GLOBAL_AS unsigned int*)(A + (size_t)gm * lda + k0 + lcol),
                    (LDS_AS unsigned int*)(&As[row * GBK + lcol]), 16, 0, 0);
            }
            int gn = bn + row; if (gn >= N) gn = N - 1;   // clamp for N<128 col-blocks
            __builtin_amdgcn_global_load_lds(
                (const GLOBAL_AS unsigned int*)(B + (size_t)gn * K + k0 + lcol),
                (LDS_AS unsigned int*)(&Bs[row * GBK + lcol]), 16, 0, 0);
        }
        __syncthreads();
#pragma unroll
        for (int ks = 0; ks < 2; ++ks) {
            v8s af[4], bfr[4];
#pragma unroll
            for (int i = 0; i < 4; ++i) {
                int row = wr * 64 + i * 16 + ln;
                af[i] = *(const v8s*)(&As[row * GBK + ks * 32 + quad * 8]);
            }
#pragma unroll
            for (int j = 0; j < 4; ++j) {
                int row = wc * 64 + j * 16 + ln;
                bfr[j] = *(const v8s*)(&Bs[row * GBK + ks * 32 + quad * 8]);
            }
#pragma unroll
            for (int i = 0; i < 4; ++i)
#pragma unroll
                for (int j = 0; j < 4; ++j)
                    acc[i][j] = __builtin_amdgcn_mfma_f32_16x16x32_bf16(af[i], bfr[j], acc[i][j], 0, 0, 0);
        }
        __syncthreads();
    }
    // epilogue: C/D layout col=lane&15, row=quad*4+reg
    if (OUT_MODE == 3) {
#pragma unroll
        for (int i = 0; i < 4; ++i) {
            int gmb = bm + wr * 64 + i * 16 + quad * 4;
            int node = gmb >> 2;
            float mx = 0.0f;
#pragma unroll
            for (int j = 0; j < 4; ++j)
#pragma unroll
                for (int r = 0; r < 4; ++r)
                    mx = fmaxf(mx, fabsf(acc[i][j][r]));
            mx = fmaxf(mx, __shfl_xor(mx, 1));
            mx = fmaxf(mx, __shfl_xor(mx, 2));
            mx = fmaxf(mx, __shfl_xor(mx, 4));
            mx = fmaxf(mx, __shfl_xor(mx, 8));
            float inv = mx > 0.0f ? 127.0f / mx : 0.0f;
#pragma unroll
            for (int j = 0; j < 4; ++j) {
                int gn = bn + wc * 64 + j * 16 + ln;
                int q0 = (int)lrintf(fminf(fmaxf(acc[i][j][0] * inv, -127.0f), 127.0f));
                int q1 = (int)lrintf(fminf(fmaxf(acc[i][j][1] * inv, -127.0f), 127.0f));
                int q2 = (int)lrintf(fminf(fmaxf(acc[i][j][2] * inv, -127.0f), 127.0f));
                int q3 = (int)lrintf(fminf(fmaxf(acc[i][j][3] * inv, -127.0f), 127.0f));
                unsigned int pk = (q0 & 0xff) | ((q1 & 0xff) << 8)
                                | ((q2 & 0xff) << 16) | ((q3 & 0xff) << 24);
                ((unsigned int*)C)[(size_t)node * D + gn] = pk;
            }
            if (ln == 0) {
                int quarter = (bn >> 6) + wc;
                Cscale[(size_t)node * 4 + quarter] = mx * (1.0f / 127.0f);
            }
        }
    } else {
#pragma unroll
        for (int i = 0; i < 4; ++i) {
            int gmb = bm + wr * 64 + i * 16 + quad * 4;
#pragma unroll
            for (int j = 0; j < 4; ++j) {
                int gn = bn + wc * 64 + j * 16 + ln;
                float bv = (bias && gn < N) ? bias[gn] : 0.0f;
                if (gn < N) {
#pragma unroll
                    for (int r = 0; r < 4; ++r) {
                        int gm = gmb + r;
                        if (gm < M) {
                            float v = acc[i][j][r] + bv;
                            if (ACT == 1) v = gelu_exact(v);
                            C[(size_t)gm * N + gn] = f2bu(v);
                        }
                    }
                }
            }
        }
    }
}

// ---------------- fused GRU step: both GEMMs + gates in one kernel ----------------
// R10-proven 64x64 tile (32 KB LDS, 1252 blocks, no bank conflicts) + `first`
// flag (h==0 on step 0 -> skip the h-phase GEMM, hold=0). R16: GRU state kept
// bf16-only — hold read from hb (same thread, read-before-write, 1:1 mapping);
// removes the f32 h buffer and ~123 MB of f32 traffic across the 4 steps.
__global__ __launch_bounds__(256) void gru_fused_kernel(
    const unsigned short* __restrict__ feat, int fstride,   // phase-0 A
    const unsigned short* __restrict__ hbf,                 // phase-1 A  [node][D]
    const unsigned short* __restrict__ Wihb,                // [3*D][D]
    const unsigned short* __restrict__ Whhb,
    const float* __restrict__ gbias,                        // [4*D] br,bz,big,bhg
    unsigned short* __restrict__ hb, int first)
{
    __shared__ short As[64 * 64];     // 8 KB
    __shared__ short Bs[192 * 64];    // 24 KB (3 gates x 64 dims)
    int tid = threadIdx.x;
    int wave = tid >> 6, lane = tid & 63;
    int ln = lane & 15, quad = lane >> 4;
    int wm = wave >> 1, wn = wave & 1;
    int bm = blockIdx.y * 64;
    int bn = blockIdx.x * 64;        // dim block

    v4f accR[2][2], accZ[2][2], accG[2][2], accHG[2][2];
#pragma unroll
    for (int mi = 0; mi < 2; ++mi)
#pragma unroll
        for (int nj = 0; nj < 2; ++nj) {
            accR[mi][nj] = (v4f)(0.0f); accZ[mi][nj] = (v4f)(0.0f);
            accG[mi][nj] = (v4f)(0.0f); accHG[mi][nj] = (v4f)(0.0f);
        }

    int lrow = lane >> 3, lcol = (lane & 7) * 8;
    int nphase = first ? 1 : 2;

    for (int phase = 0; phase < nphase; ++phase) {
        const unsigned short* A = phase ? hbf : feat;
        int astr = phase ? D : fstride;
        const unsigned short* W = phase ? Whhb : Wihb;
        for (int k0 = 0; k0 < D; k0 += 64) {
#pragma unroll
            for (int c = 0; c < 2; ++c) {
                int row = wave * 16 + c * 8 + lrow;
                int gm = bm + row; if (gm >= Nn) gm = Nn - 1;
                __builtin_amdgcn_global_load_lds(
                    (const GLOBAL_AS unsigned int*)(A + (size_t)gm * astr + k0 + lcol),
                    (LDS_AS unsigned int*)(&As[row * 64 + lcol]), 16, 0, 0);
            }
#pragma unroll
            for (int c = 0; c < 6; ++c) {
                int row = wave * 48 + c * 8 + lrow;   // 0..191
                int g = row >> 6, dloc = row & 63;
                __builtin_amdgcn_global_load_lds(
                    (const GLOBAL_AS unsigned int*)(W + ((size_t)(g * D + bn + dloc)) * D + k0 + lcol),
                    (LDS_AS unsigned int*)(&Bs[row * 64 + lcol]), 16, 0, 0);
            }
            __syncthreads();
#pragma unroll
            for (int ks = 0; ks < 2; ++ks) {
                v8s am[2];
#pragma unroll
                for (int mi = 0; mi < 2; ++mi)
                    am[mi] = *(const v8s*)(&As[(wm * 32 + mi * 16 + ln) * 64 + ks * 32 + quad * 8]);
#pragma unroll
                for (int g = 0; g < 3; ++g) {
#pragma unroll
                    for (int nj = 0; nj < 2; ++nj) {
                        v8s bf = *(const v8s*)(&Bs[(g * 64 + wn * 32 + nj * 16 + ln) * 64 + ks * 32 + quad * 8]);
#pragma unroll
                        for (int mi = 0; mi < 2; ++mi) {
                            if (g == 0)
                                accR[mi][nj] = __builtin_amdgcn_mfma_f32_16x16x32_bf16(am[mi], bf, accR[mi][nj], 0, 0, 0);
                            else if (g == 1)
                                accZ[mi][nj] = __builtin_amdgcn_mfma_f32_16x16x32_bf16(am[mi], bf, accZ[mi][nj], 0, 0, 0);
                            else if (phase == 0)
                                accG[mi][nj] = __builtin_amdgcn_mfma_f32_16x16x32_bf16(am[mi], bf, accG[mi][nj], 0, 0, 0);
                            else
                                accHG[mi][nj] = __builtin_amdgcn_mfma_f32_16x16x32_bf16(am[mi], bf, accHG[mi][nj], 0, 0, 0);
                        }
                    }
                }
            }
            __syncthreads();
        }
    }
#pragma unroll
    for (int mi = 0; mi < 2; ++mi) {
        int gm0 = bm + wm * 32 + mi * 16 + quad * 4;
#pragma unroll
        for (int nj = 0; nj < 2; ++nj) {
            int gn = bn + wn * 32 + nj * 16 + ln;
            float vbr = gbias[gn], vbz = gbias[D + gn];
            float vbig = gbias[2 * D + gn], vbhg = gbias[3 * D + gn];
#pragma unroll
            for (int r = 0; r < 4; ++r) {
                int gm = gm0 + r;
                if (gm < Nn) {
                    float rv = 1.0f / (1.0f + expf(-(accR[mi][nj][r] + vbr)));
                    float zv = 1.0f / (1.0f + expf(-(accZ[mi][nj][r] + vbz)));
                    float nv = tanhf(accG[mi][nj][r] + vbig + rv * (accHG[mi][nj][r] + vbhg));
                    float hold = first ? 0.0f : b2f(hb[(size_t)gm * D + gn]);
                    float hv = (1.0f - zv) * nv + zv * hold;
                    hb[(size_t)gm * D + gn] = f2bu(hv);
                }
            }
        }
    }
}

// ------- GCN aggregate (4 snapshots, int8 table) + bias + LN + ReLU, wave/node ----
__global__ __launch_bounds__(256) void gcn_agg_ln_relu4_kernel(
    const unsigned int* __restrict__ tbl8, const float4* __restrict__ scales,
    const int* __restrict__ rowptr,
    const int* __restrict__ csrc, const float* __restrict__ cnorm,
    const float* __restrict__ selfnorm,
    const float* __restrict__ gcn_b, const float* __restrict__ ln_g,
    const float* __restrict__ ln_b, unsigned short* __restrict__ out)
{
    int wave = threadIdx.x >> 6, lane = threadIdx.x & 63;
    int i = blockIdx.x * 4 + wave;

    float acc[4][4];   // [q dim-seg][s snap]
    {
        float w = selfnorm[i];
        float4 sc = scales[i];
        float wq[4] = {w * sc.x, w * sc.y, w * sc.z, w * sc.w};
#pragma unroll
        for (int q = 0; q < 4; ++q) {
            unsigned int v = tbl8[(size_t)i * D + lane + q * 64];
            acc[q][0] = wq[q] * sx0(v); acc[q][1] = wq[q] * sx1(v);
            acc[q][2] = wq[q] * sx2(v); acc[q][3] = wq[q] * sx3(v);
        }
    }
    int beg = rowptr[i], end = rowptr[i + 1];
    int p = beg;
    for (; p + 1 < end; p += 2) {
        int sA = csrc[p], sB = csrc[p + 1];
        float wA = cnorm[p], wB = cnorm[p + 1];
        float4 scA = scales[sA], scB = scales[sB];
        unsigned int uA[4], uB[4];
#pragma unroll
        for (int q = 0; q < 4; ++q) {
            uA[q] = tbl8[(size_t)sA * D + lane + q * 64];
            uB[q] = tbl8[(size_t)sB * D + lane + q * 64];
        }
        float wqA[4] = {wA * scA.x, wA * scA.y, wA * scA.z, wA * scA.w};
        float wqB[4] = {wB * scB.x, wB * scB.y, wB * scB.z, wB * scB.w};
#pragma unroll
        for (int q = 0; q < 4; ++q) {
            acc[q][0] = fmaf(wqA[q], sx0(uA[q]), acc[q][0]);
            acc[q][1] = fmaf(wqA[q], sx1(uA[q]), acc[q][1]);
            acc[q][2] = fmaf(wqA[q], sx2(uA[q]), acc[q][2]);
            acc[q][3] = fmaf(wqA[q], sx3(uA[q]), acc[q][3]);
            acc[q][0] = fmaf(wqB[q], sx0(uB[q]), acc[q][0]);
            acc[q][1] = fmaf(wqB[q], sx1(uB[q]), acc[q][1]);
            acc[q][2] = fmaf(wqB[q], sx2(uB[q]), acc[q][2]);
            acc[q][3] = fmaf(wqB[q], sx3(uB[q]), acc[q][3]);
        }
    }
    if (p < end) {
        int sA = csrc[p]; float wA = cnorm[p];
        float4 scA = scales[sA];
        float wqA[4] = {wA * scA.x, wA * scA.y, wA * scA.z, wA * scA.w};
#pragma unroll
        for (int q = 0; q < 4; ++q) {
            unsigned int v = tbl8[(size_t)sA * D + lane + q * 64];
            acc[q][0] = fmaf(wqA[q], sx0(v), acc[q][0]);
            acc[q][1] = fmaf(wqA[q], sx1(v), acc[q][1]);
            acc[q][2] = fmaf(wqA[q], sx2(v), acc[q][2]);
            acc[q][3] = fmaf(wqA[q], sx3(v), acc[q][3]);
        }
    }
#pragma unroll
    for (int q = 0; q < 4; ++q) {
        float bb = gcn_b[lane + q * 64];
        acc[q][0] += bb; acc[q][1] += bb; acc[q][2] += bb; acc[q][3] += bb;
    }
    float s1[4], s2[4];
#pragma unroll
    for (int s = 0; s < 4; ++s) {
        s1[s] = acc[0][s] + acc[1][s] + acc[2][s] + acc[3][s];
        s2[s] = acc[0][s] * acc[0][s] + acc[1][s] * acc[1][s]
              + acc[2][s] * acc[2][s] + acc[3][s] * acc[3][s];
    }
#pragma unroll
    for (int off = 32; off > 0; off >>= 1) {
#pragma unroll
        for (int s = 0; s < 4; ++s) {
            s1[s] += __shfl_xor(s1[s], off);
            s2[s] += __shfl_xor(s2[s], off);
        }
    }
    const float inv = 1.0f / D;
    float m[4], rr[4];
#pragma unroll
    for (int s = 0; s < 4; ++s) {
        m[s] = s1[s] * inv;
        rr[s] = rsqrtf(s2[s] * inv - m[s] * m[s] + 1e-5f);
    }
    size_t ob = (size_t)(i << 2) * D;
#pragma unroll
    for (int q = 0; q < 4; ++q) {
        int d = lane + q * 64;
        float g = ln_g[d], lb = ln_b[d];
#pragma unroll
        for (int s = 0; s < 4; ++s) {
            float y = (acc[q][s] - m[s]) * rr[s] * g + lb;
            out[ob + (size_t)s * D + d] = f2bu(fmaxf(y, 0.0f));
        }
    }
}

// ------- small output head: C[M,5] = A_bf16[M,K](lda) * W[5,K]^T + b --------------
__global__ void head5_bf_kernel(const unsigned short* __restrict__ A, int lda,
                                const float* __restrict__ W,
                                const float* __restrict__ b, float* __restrict__ C,
                                int M, int K) {
    int idx = blockIdx.x * blockDim.x + threadIdx.x;
    if (idx >= M * H) return;
    int m = idx / H;
    int h = idx - m * H;
    const ushort4* ar = (const ushort4*)(A + (size_t)m * lda);
    const float* wr = W + (size_t)h * K;
    float s = 0.0f;
    for (int k4 = 0; k4 < K / 4; ++k4) {
        ushort4 u = ar[k4];
        s = fmaf(b2f(u.x), wr[4 * k4 + 0], s);
        s = fmaf(b2f(u.y), wr[4 * k4 + 1], s);
        s = fmaf(b2f(u.z), wr[4 * k4 + 2], s);
        s = fmaf(b2f(u.w), wr[4 * k4 + 3], s);
    }
    C[idx] = s + b[h];
}

extern "C" void kernel_launch(void* const* d_in, const int* in_sizes, int n_in,
                              void* d_out, int out_size, void* d_ws, size_t ws_size,
                              hipStream_t stream)
{
    const float* x     = (const float*)d_in[0];
    const int*   esrc  = (const int*)d_in[1];
    const int*   edst  = (const int*)d_in[2];
    const float* ew    = (const float*)d_in[3];
    const float* gcn_W = (const float*)d_in[4];
    const float* gcn_b = (const float*)d_in[5];
    const float* ln_g  = (const float*)d_in[6];
    const float* ln_b  = (const float*)d_in[7];
    const float* Wih   = (const float*)d_in[8];
    const float* Whh   = (const float*)d_in[9];
    const float* bih   = (const float*)d_in[10];
    const float* bhh   = (const float*)d_in[11];
    const float* fc1W  = (const float*)d_in[12];
    const float* fc1b  = (const float*)d_in[13];
    const float* fc2W  = (const float*)d_in[14];
    const float* fc2b  = (const float*)d_in[15];
    const float* fc3W  = (const float*)d_in[16];
    const float* fc3b  = (const float*)d_in[17];
    const float* dh1W  = (const float*)d_in[18];
    const float* dh1b  = (const float*)d_in[19];
    const float* dh2W  = (const float*)d_in[20];
    const float* dh2b  = (const float*)d_in[21];

    float* out = (float*)d_out;   // [Nn*H forecast][Nn*H direction]

    // workspace carve-out (aligned to 256B); total ~91 MB
    char* p = (char*)d_ws;
    auto alloc = [&](size_t bytes) -> void* {
        void* r = (void*)p;
        p += (bytes + 255) & ~(size_t)255;
        return r;
    };
    float* deg      = (float*)alloc((size_t)Nn * 4);
    float* dinv     = (float*)alloc((size_t)Nn * 4);
    float* selfnorm = (float*)alloc((size_t)Nn * 4);
    int*   rowptr   = (int*)alloc((size_t)(Nn + 1) * 4);
    int*   cnt      = (int*)alloc((size_t)Nn * 4);
    int*   csrc     = (int*)alloc((size_t)E * 4);
    float* cnorm    = (float*)alloc((size_t)E * 4);
    unsigned short* Wtb      = (unsigned short*)alloc((size_t)L * D * D * 2);
    unsigned short* Wihb     = (unsigned short*)alloc((size_t)3 * D * D * 2);
    unsigned short* Whhb     = (unsigned short*)alloc((size_t)3 * D * D * 2);
    unsigned short* fc1dh1Wb = (unsigned short*)alloc((size_t)192 * 256 * 2);
    unsigned short* fc2Wb    = (unsigned short*)alloc((size_t)64 * 128 * 2);
    float* gbias    = (float*)alloc((size_t)4 * D * 4);
    float* hcat     = (float*)alloc((size_t)192 * 4);
    unsigned short* bufA  = (unsigned short*)alloc((size_t)Nn * S * D * 2);    // 41MB
    unsigned int*   tbl8  = (unsigned int*)alloc((size_t)Nn * D * 4);          // 20.5MB int8 table
    float*          tscal = (float*)alloc((size_t)Nn * 4 * 4);                 // 320KB float4 scales
    unsigned short* hgru_bf = (unsigned short*)alloc((size_t)Nn * D * 2);      // 10.2MB
    unsigned short* f1cat = (unsigned short*)alloc((size_t)Nn * 192 * 2);      // 7.7MB
    unsigned short* f2    = (unsigned short*)alloc((size_t)Nn * 64 * 2);       // 2.6MB

    auto cdiv = [](int a, int b) { return (a + b - 1) / b; };

    // ---- graph + weight preprocessing ----
    init_deg_cnt_kernel<<<cdiv(Nn, 256), 256, 0, stream>>>(deg, cnt, Nn);
    deg_hist_kernel<<<cdiv(E, 256), 256, 0, stream>>>(edst, ew, deg, cnt, E);
    dinv_kernel<<<cdiv(Nn, 256), 256, 0, stream>>>(deg, dinv, selfnorm, Nn);
    scan_rowptr_kernel<<<1, 1024, 0, stream>>>(cnt, rowptr, Nn);
    csr_fill_kernel<<<cdiv(E, 256), 256, 0, stream>>>(esrc, edst, ew, dinv, rowptr, cnt, csrc, cnorm, E);
    convert_weights_kernel<<<cdiv(CW6, 256), 256, 0, stream>>>(
        gcn_W, Wih, Whh, fc1W, fc2W, dh1W, bih, bhh, fc1b, dh1b,
        Wtb, Wihb, Whhb, fc1dh1Wb, fc2Wb, gbias, hcat);

    // ---- batched GCN stack: all 4 snapshots at once; int8 gather table ----
    {
        dim3 g1(D / GBN, (Nn * S) / GBM);   // (2, 625)
        gemm_bt_bf16_kernel<3, 0, 1><<<g1, 256, 0, stream>>>(
            (const unsigned short*)x, D, Wtb, nullptr, (unsigned short*)tbl8, tscal,
            Nn * S, D, D);
        gcn_agg_ln_relu4_kernel<<<Nn / 4, 256, 0, stream>>>(
            tbl8, (const float4*)tscal, rowptr, csrc, cnorm, selfnorm,
            gcn_b, ln_g, ln_b, bufA);
        for (int l = 1; l < L; ++l) {
            gemm_bt_bf16_kernel<3, 0, 0><<<g1, 256, 0, stream>>>(
                bufA, D, Wtb + (size_t)l * D * D, nullptr, (unsigned short*)tbl8, tscal,
                Nn * S, D, D);
            gcn_agg_ln_relu4_kernel<<<Nn / 4, 256, 0, stream>>>(
                tbl8, (const float4*)tscal, rowptr, csrc, cnorm, selfnorm,
                gcn_b + (size_t)l * D, ln_g + (size_t)l * D, ln_b + (size_t)l * D, bufA);
        }
    }

    // ---- fused GRU loop (1 kernel per snapshot; s=0 skips the h-phase) ----
    for (int s = 0; s < S; ++s) {
        dim3 g2(D / 64, cdiv(Nn, 64));   // (4, 313)
        gru_fused_kernel<<<g2, 256, 0, stream>>>(
            bufA + (size_t)s * D, S * D, hgru_bf, Wihb, Whhb, gbias,
            hgru_bf, (s == 0) ? 1 : 0);
    }

    // ---- heads: merged fc1+dh1 GEMM, fc2 GEMM, two small head kernels (R13 form) --
    {
        dim3 gf1(2, cdiv(Nn, GBM));   // N=192 -> 2 col-blocks
        gemm_bt_bf16_kernel<1, 1, 0><<<gf1, 256, 0, stream>>>(
            hgru_bf, D, fc1dh1Wb, hcat, f1cat, nullptr, Nn, 192, 256);
        dim3 gf2(1, cdiv(Nn, GBM));
        gemm_bt_bf16_kernel<1, 1, 0><<<gf2, 256, 0, stream>>>(
            f1cat, 192, fc2Wb, fc2b, f2, nullptr, Nn, 64, 128);
        head5_bf_kernel<<<cdiv(Nn * H, 256), 256, 0, stream>>>(f2, 64, fc3W, fc3b, out, Nn, 64);
        head5_bf_kernel<<<cdiv(Nn * H, 256), 256, 0, stream>>>(f1cat + 128, 192, dh2W, dh2b,
                                                               out + (size_t)Nn * H, Nn, 64);
    }
}